// Round 11
// baseline (254.742 us; speedup 1.0000x reference)
//
#include <hip/hip_runtime.h>
#include <hip/hip_bf16.h>
#include <stdint.h>

// Transformer layer: S=2048, B=2, D=1024, H=16, DH=64, FF=4096. fp32 in/out.
// Strategy: fp32 LN/softmax/accum, bf16 MFMA (16x16x32) for all GEMMs.

#define S_LEN 2048
#define BATCH 2
#define DMODEL 1024
#define NHEAD 16
#define DHEAD 64
#define FFDIM 4096
#define MROWS (S_LEN * BATCH)  // 4096 rows, row index = s*B + b

typedef unsigned short u16;
typedef __attribute__((ext_vector_type(8))) __bf16 bf16x8;
typedef __attribute__((ext_vector_type(4))) float f32x4;
typedef __attribute__((ext_vector_type(4))) u16 u16x4;

__device__ inline u16 f2bf(float f) {
  union { float f; unsigned u; } v; v.f = f;
  unsigned r = v.u + 0x7fffu + ((v.u >> 16) & 1u);  // round-to-nearest-even
  return (u16)(r >> 16);
}

__device__ inline f32x4 mfma16(bf16x8 a, bf16x8 b, f32x4 c) {
  return __builtin_amdgcn_mfma_f32_16x16x32_bf16(a, b, c, 0, 0, 0);
}

// async global->LDS, 16B per lane. LDS dest must be wave-uniform base; HW adds lane*16.
__device__ inline void gload_lds16(const u16* g, u16* l) {
  __builtin_amdgcn_global_load_lds(
      (const __attribute__((address_space(1))) unsigned int*)g,
      (__attribute__((address_space(3))) unsigned int*)l, 16, 0, 0);
}

__device__ inline uint32_t cvt_pk_bf16(float lo, float hi) {
  uint32_t r;
  asm("v_cvt_pk_bf16_f32 %0, %1, %2" : "=v"(r) : "v"(lo), "v"(hi));
  return r;
}

// ---------------- LayerNorm: fp32 in -> bf16 out ----------------
__global__ __launch_bounds__(256) void ln_kernel(const float* __restrict__ x,
                                                 const float* __restrict__ gam,
                                                 const float* __restrict__ bet,
                                                 u16* __restrict__ out) {
  int row = blockIdx.x;
  int tid = threadIdx.x;
  const float4* xr = (const float4*)(x + (size_t)row * DMODEL);
  float4 v = xr[tid];
  float s = v.x + v.y + v.z + v.w;
  float ss = v.x * v.x + v.y * v.y + v.z * v.z + v.w * v.w;
#pragma unroll
  for (int m = 1; m < 64; m <<= 1) {
    s += __shfl_xor(s, m);
    ss += __shfl_xor(ss, m);
  }
  __shared__ float red[8];
  int w = tid >> 6, lane = tid & 63;
  if (lane == 0) { red[w] = s; red[4 + w] = ss; }
  __syncthreads();
  s = red[0] + red[1] + red[2] + red[3];
  ss = red[4] + red[5] + red[6] + red[7];
  float mu = s * (1.f / DMODEL);
  float var = ss * (1.f / DMODEL) - mu * mu;
  float rstd = rsqrtf(var + 1e-5f);
  float4 gv = ((const float4*)gam)[tid];
  float4 bv = ((const float4*)bet)[tid];
  u16x4 o;
  o.x = f2bf((v.x - mu) * rstd * gv.x + bv.x);
  o.y = f2bf((v.y - mu) * rstd * gv.y + bv.y);
  o.z = f2bf((v.z - mu) * rstd * gv.z + bv.z);
  o.w = f2bf((v.w - mu) * rstd * gv.w + bv.w);
  *(u16x4*)(out + (size_t)row * DMODEL + tid * 4) = o;
}

// ---------------- fused weight transpose-cast: all 6 weights in ONE launch ----------------
__global__ __launch_bounds__(256) void transpose_all(const float* __restrict__ wq,
                                                     const float* __restrict__ wk,
                                                     const float* __restrict__ wv,
                                                     const float* __restrict__ wo,
                                                     const float* __restrict__ w1,
                                                     const float* __restrict__ w2,
                                                     u16* __restrict__ wqkvt, u16* __restrict__ wot,
                                                     u16* __restrict__ w1t, u16* __restrict__ w2t) {
  int idx = blockIdx.x;
  const float* in;
  u16* out;
  int R, C;
  if (idx < 3072) {
    int which = idx >> 10;
    in = (which == 0) ? wq : (which == 1) ? wk : wv;
    out = wqkvt + (size_t)which * 1024 * 1024;
    R = 1024; C = 1024;
    idx &= 1023;
  } else if (idx < 4096) {
    in = wo; out = wot; R = 1024; C = 1024; idx -= 3072;
  } else if (idx < 8192) {
    in = w1; out = w1t; R = 1024; C = 4096; idx -= 4096;
  } else {
    in = w2; out = w2t; R = 4096; C = 1024; idx -= 8192;
  }
  int ntx = C >> 5;
  int tc = idx % ntx, tr = idx / ntx;
  int c0 = tc * 32, r0 = tr * 32;
  __shared__ u16 tile[32][33];
  int tx = threadIdx.x & 31, grp = threadIdx.x >> 5;
#pragma unroll
  for (int i = 0; i < 4; i++) {
    int r = grp * 4 + i;
    tile[r][tx] = f2bf(in[(size_t)(r0 + r) * C + c0 + tx]);
  }
  __syncthreads();
#pragma unroll
  for (int i = 0; i < 4; i++) {
    int rr = grp * 4 + i;
    out[(size_t)(c0 + rr) * R + r0 + tx] = tile[tx][rr];
  }
}

// ---------------- V slice of qkv -> Vt[bh][dh][s] ----------------
__global__ __launch_bounds__(256) void transpose_v(const u16* __restrict__ qkv,
                                                   u16* __restrict__ vt) {
  __shared__ u16 tile[32][33];
  int bh = blockIdx.z;
  int b = bh >> 4;
  int s0 = blockIdx.x * 32, d0 = blockIdx.y * 32;
  int h = bh & 15;
  int tx = threadIdx.x & 31, grp = threadIdx.x >> 5;
#pragma unroll
  for (int i = 0; i < 4; i++) {
    int sl = grp * 4 + i;
    tile[sl][tx] = qkv[(size_t)((s0 + sl) * BATCH + b) * 3072 + 2048 + h * DHEAD + d0 + tx];
  }
  __syncthreads();
#pragma unroll
  for (int i = 0; i < 4; i++) {
    int dl = grp * 4 + i;
    vt[((size_t)bh * DHEAD + d0 + dl) * S_LEN + s0 + tx] = tile[tx][dl];
  }
}

// ---------------- GEMM (R5/R8-proven): BK=64, XOR-swizzled LDS, counted-vmcnt 2-phase ----------------
// C[M][N] = A[M][K](bf16) @ Bt[N][K](bf16)^T.  BM=128, BN in {128,64}, 4 waves.
// MODE 0: bf16 out.  MODE 2: bf16 out = relu(acc + bias).
template <int MODE, int BN>
__global__ __launch_bounds__(256) void gemm_bt(const u16* __restrict__ A,
                                               const u16* __restrict__ Bt, void* __restrict__ Cout,
                                               const float* __restrict__ bias,
                                               const float* __restrict__ res, int M, int N, int K) {
  __shared__ __align__(16) u16 As[2][128 * 64];
  __shared__ __align__(16) u16 Bs[2][BN * 64];
  constexpr int NLOADS = 4 + BN / 32;

  int nwg = gridDim.x * gridDim.y;
  int f = blockIdx.y * gridDim.x + blockIdx.x;
  int nf = ((nwg & 7) == 0) ? ((f & 7) * (nwg >> 3) + (f >> 3)) : f;
  int bx = nf % gridDim.x, by = nf / gridDim.x;

  int bm0 = by * 128, bn0 = bx * BN;
  int tid = threadIdx.x, w = tid >> 6, lane = tid & 63;
  int g = lane >> 4, l15 = lane & 15;
  int lr = lane >> 3, ch = lane & 7;
  int srcch = (ch ^ lr) * 8;  // pre-swizzled 16B-chunk column offset (rule 21c)
  int wm = (w >> 1) * 64, wn = (w & 1) * (BN / 2);
  const int NJ = BN / 32;

  f32x4 acc[4][NJ];
#pragma unroll
  for (int i = 0; i < 4; i++)
#pragma unroll
    for (int j = 0; j < NJ; j++) {
      f32x4 z = {0.f, 0.f, 0.f, 0.f};
      acc[i][j] = z;
    }

  auto stage = [&](int k0, int buf) {
#pragma unroll
    for (int rd = 0; rd < 4; rd++) {
      int rb = (rd * 4 + w) * 8;  // lane's row = rb + lr; row&7 == lr
      gload_lds16(A + (size_t)(bm0 + rb + lr) * K + k0 + srcch, &As[buf][rb * 64]);
    }
#pragma unroll
    for (int rd = 0; rd < BN / 32; rd++) {
      int rb = (rd * 4 + w) * 8;
      gload_lds16(Bt + (size_t)(bn0 + rb + lr) * K + k0 + srcch, &Bs[buf][rb * 64]);
    }
  };

  int nkt = K >> 6;
  stage(0, 0);
  asm volatile("s_waitcnt vmcnt(0)" ::: "memory");
  __builtin_amdgcn_s_barrier();

  for (int kt = 0; kt < nkt; ++kt) {
    int cur = kt & 1;
    if (kt + 1 < nkt) {
      stage((kt + 1) << 6, cur ^ 1);
      asm volatile("s_waitcnt vmcnt(%0)" ::"n"(NLOADS) : "memory");
    } else {
      asm volatile("s_waitcnt vmcnt(0)" ::: "memory");
    }
    __builtin_amdgcn_s_barrier();
#pragma unroll
    for (int kk = 0; kk < 2; kk++) {
      bf16x8 af[4], bfr[NJ];
#pragma unroll
      for (int i = 0; i < 4; i++) {
        int row = wm + i * 16 + l15;
        af[i] = *(const bf16x8*)&As[cur][row * 64 + (((kk * 4 + g) ^ (row & 7)) * 8)];
      }
#pragma unroll
      for (int j = 0; j < NJ; j++) {
        int row = wn + j * 16 + l15;
        bfr[j] = *(const bf16x8*)&Bs[cur][row * 64 + (((kk * 4 + g) ^ (row & 7)) * 8)];
      }
#pragma unroll
      for (int i = 0; i < 4; i++)
#pragma unroll
        for (int j = 0; j < NJ; j++) acc[i][j] = mfma16(af[i], bfr[j], acc[i][j]);
    }
    __builtin_amdgcn_s_barrier();
  }

  // epilogue: D layout col = lane&15, row = 4*(lane>>4) + r
#pragma unroll
  for (int i = 0; i < 4; i++)
#pragma unroll
    for (int j = 0; j < NJ; j++) {
      int col = bn0 + wn + j * 16 + l15;
      float bval = (MODE == 2 || MODE == 3) ? bias[col] : 0.f;
#pragma unroll
      for (int r = 0; r < 4; r++) {
        int row = bm0 + wm + i * 16 + g * 4 + r;
        size_t idx = (size_t)row * N + col;
        float vacc = acc[i][j][r] + bval;
        if (MODE == 0)
          ((u16*)Cout)[idx] = f2bf(vacc);
        else if (MODE == 1)
          ((float*)Cout)[idx] = vacc + res[idx];
        else if (MODE == 2)
          ((u16*)Cout)[idx] = f2bf(fmaxf(vacc, 0.f));
        else
          ((float*)Cout)[idx] = vacc + res[idx];
      }
    }
}

// ---------------- GEMM wide-M for N=1024 cases: BM=256, BN=64, 8 waves (4Mx2N) ----------------
// Same proven 2-phase counted-vmcnt loop; 32 MFMA per tile per wave (2x the 128x64
// config) so per-tile barrier overhead halves. Grid = (N/64)x(M/256) = 256 blocks
// = exactly 1 block/CU (no tail), 8 waves/CU. LDS 80KB. Loads/wave/stage = 4A+1B=5.
// MODE 1: fp32 out = acc + res.  MODE 3: fp32 out = acc + bias + res.
template <int MODE>
__global__ __launch_bounds__(512) void gemm_bt8(const u16* __restrict__ A,
                                                const u16* __restrict__ Bt,
                                                void* __restrict__ Cout,
                                                const float* __restrict__ bias,
                                                const float* __restrict__ res, int M, int N,
                                                int K) {
  __shared__ __align__(16) u16 As[2][256 * 64];
  __shared__ __align__(16) u16 Bs[2][64 * 64];
  constexpr int NLOADS = 5;

  int nwg = gridDim.x * gridDim.y;
  int f = blockIdx.y * gridDim.x + blockIdx.x;
  int nf = ((nwg & 7) == 0) ? ((f & 7) * (nwg >> 3) + (f >> 3)) : f;
  int bx = nf % gridDim.x, by = nf / gridDim.x;

  int bm0 = by * 256, bn0 = bx * 64;
  int tid = threadIdx.x, w = tid >> 6, lane = tid & 63;
  int g = lane >> 4, l15 = lane & 15;
  int lr = lane >> 3, ch = lane & 7;
  int srcch = (ch ^ lr) * 8;
  int wm = (w >> 1) * 64, wn = (w & 1) * 32;  // 4M x 2N waves; wave tile 64x32

  f32x4 acc[4][2];
#pragma unroll
  for (int i = 0; i < 4; i++)
#pragma unroll
    for (int j = 0; j < 2; j++) {
      f32x4 z = {0.f, 0.f, 0.f, 0.f};
      acc[i][j] = z;
    }

  auto stage = [&](int k0, int buf) {
#pragma unroll
    for (int rd = 0; rd < 4; rd++) {
      int rb = (rd * 8 + w) * 8;  // rows 0..255; lane's row = rb + lr; row&7 == lr
      gload_lds16(A + (size_t)(bm0 + rb + lr) * K + k0 + srcch, &As[buf][rb * 64]);
    }
    {
      int rb = w * 8;  // rows 0..63
      gload_lds16(Bt + (size_t)(bn0 + rb + lr) * K + k0 + srcch, &Bs[buf][rb * 64]);
    }
  };

  int nkt = K >> 6;
  stage(0, 0);
  asm volatile("s_waitcnt vmcnt(0)" ::: "memory");
  __builtin_amdgcn_s_barrier();

  for (int kt = 0; kt < nkt; ++kt) {
    int cur = kt & 1;
    if (kt + 1 < nkt) {
      stage((kt + 1) << 6, cur ^ 1);
      asm volatile("s_waitcnt vmcnt(%0)" ::"n"(NLOADS) : "memory");
    } else {
      asm volatile("s_waitcnt vmcnt(0)" ::: "memory");
    }
    __builtin_amdgcn_s_barrier();
#pragma unroll
    for (int kk = 0; kk < 2; kk++) {
      bf16x8 af[4], bfr[2];
#pragma unroll
      for (int i = 0; i < 4; i++) {
        int row = wm + i * 16 + l15;
        af[i] = *(const bf16x8*)&As[cur][row * 64 + (((kk * 4 + g) ^ (row & 7)) * 8)];
      }
#pragma unroll
      for (int j = 0; j < 2; j++) {
        int row = wn + j * 16 + l15;
        bfr[j] = *(const bf16x8*)&Bs[cur][row * 64 + (((kk * 4 + g) ^ (row & 7)) * 8)];
      }
#pragma unroll
      for (int i = 0; i < 4; i++)
#pragma unroll
        for (int j = 0; j < 2; j++) acc[i][j] = mfma16(af[i], bfr[j], acc[i][j]);
    }
    __builtin_amdgcn_s_barrier();
  }

#pragma unroll
  for (int i = 0; i < 4; i++)
#pragma unroll
    for (int j = 0; j < 2; j++) {
      int col = bn0 + wn + j * 16 + l15;
      float bval = (MODE == 3) ? bias[col] : 0.f;
#pragma unroll
      for (int r = 0; r < 4; r++) {
        int row = bm0 + wm + i * 16 + g * 4 + r;
        size_t idx = (size_t)row * N + col;
        ((float*)Cout)[idx] = acc[i][j][r] + bval + res[idx];
      }
    }
}

// ---------------- flash attention v7: deferred-PV pipeline (T15) ----------------
// grid (S/64, B*H) XCD-chunked, 256 thr = 4 waves; wave owns 16 q rows.
// Swapped mfma(K,Q): lane holds S^T[t][q=l15]. Frozen max after tile 0; denominator
// via ones-MFMA. PV deferred one tile: iteration t runs QK(t), PV(t-1) from registers,
// V-frag loads(t), softmax(t). lgkmcnt(0) before end barrier protects deferred V reads.
__global__ __launch_bounds__(256) void attn_kernel(const u16* __restrict__ qkv,
                                                   const u16* __restrict__ vt,
                                                   u16* __restrict__ ctx) {
  int nwg = gridDim.x * gridDim.y;  // 1024
  int f = blockIdx.y * gridDim.x + blockIdx.x;
  int nf = (f & 7) * (nwg >> 3) + (f >> 3);
  int qblk = nf % gridDim.x, bh = nf / gridDim.x;
  int b = bh >> 4, h = bh & 15;
  int tid = threadIdx.x, w = tid >> 6, lane = tid & 63;
  int g = lane >> 4, l15 = lane & 15;
  int lr = lane >> 3, ch = lane & 7;
  int q0 = qblk * 64 + w * 16;
  const float SCALE = 0.125f * 1.44269504f;  // 1/sqrt(64) * log2(e)

  __shared__ __align__(16) u16 ks[2][64 * 64];
  __shared__ __align__(16) u16 vs[2][64 * 64];

  bf16x8 qf0, qf1;
  {
    const u16* qp = qkv + ((size_t)(q0 + l15) * BATCH + b) * 3072 + h * DHEAD;
    qf0 = *(const bf16x8*)(qp + g * 8);
    qf1 = *(const bf16x8*)(qp + 32 + g * 8);
  }
  bf16x8 onef;
  {
    union { u16 u[8]; bf16x8 v; } ou;
#pragma unroll
    for (int i = 0; i < 8; i++) ou.u[i] = 0x3F80;  // bf16 1.0
    onef = ou.v;
  }

  f32x4 accT[4];
#pragma unroll
  for (int n = 0; n < 4; n++) {
    f32x4 z = {0.f, 0.f, 0.f, 0.f};
    accT[n] = z;
  }
  f32x4 lacc = {0.f, 0.f, 0.f, 0.f};  // denominator (all rows equal)
  float negms = 0.f;                  // = -max_tile0 * SCALE, set at it==0
  bf16x8 pbp[2];                      // P frags of previous tile
  bf16x8 vfp[4][2];                   // V frags of previous tile

  auto stage = [&](int t0, int buf) {
#pragma unroll
    for (int rd = 0; rd < 2; rd++) {
      int rb = w * 16 + rd * 8;
      int row = rb + lr;
      const u16* ksrc =
          qkv + ((size_t)(t0 + row) * BATCH + b) * 3072 + 1024 + h * DHEAD + (ch ^ lr) * 8;
      gload_lds16(ksrc, &ks[buf][rb * 64]);
      const u16* vsrc = vt + ((size_t)bh * DHEAD + row) * S_LEN + t0 + (ch ^ lr) * 8;
      gload_lds16(vsrc, &vs[buf][rb * 64]);
    }
  };

  stage(0, 0);
  asm volatile("s_waitcnt vmcnt(0)" ::: "memory");
  __builtin_amdgcn_s_barrier();

  for (int it = 0; it < S_LEN / 64; ++it) {
    int cur = it & 1;
    if (it + 1 < S_LEN / 64) {
      stage((it + 1) * 64, cur ^ 1);
      asm volatile("s_waitcnt vmcnt(4)" ::: "memory");
    } else {
      asm volatile("s_waitcnt vmcnt(0)" ::: "memory");
    }
    __builtin_amdgcn_s_barrier();

    // ---- QK^T(t) (swapped): scT[tt][r] = S_raw^T[16tt+4g+r][q0+l15] ----
    f32x4 scT[4];
#pragma unroll
    for (int tt = 0; tt < 4; tt++) {
      int row = tt * 16 + l15;
      bf16x8 kf0 = *(const bf16x8*)&ks[cur][row * 64 + ((g ^ (row & 7)) * 8)];
      bf16x8 kf1 = *(const bf16x8*)&ks[cur][row * 64 + (((4 + g) ^ (row & 7)) * 8)];
      f32x4 z = {0.f, 0.f, 0.f, 0.f};
      __builtin_amdgcn_s_setprio(1);
      z = mfma16(kf0, qf0, z);
      z = mfma16(kf1, qf1, z);
      __builtin_amdgcn_s_setprio(0);
      scT[tt] = z;
    }

    // ---- PV(t-1) + denominator: pure-register MFMA, independent of softmax(t) ----
    if (it > 0) {
      __builtin_amdgcn_s_setprio(1);
      lacc = mfma16(onef, pbp[0], lacc);
      lacc = mfma16(onef, pbp[1], lacc);
#pragma unroll
      for (int n = 0; n < 4; n++) {
        accT[n] = mfma16(vfp[n][0], pbp[0], accT[n]);
        accT[n] = mfma16(vfp[n][1], pbp[1], accT[n]);
      }
      __builtin_amdgcn_s_setprio(0);
    }

    // ---- load V(t) frags (consumed next iter); overlaps softmax VALU below ----
#pragma unroll
    for (int n = 0; n < 4; n++) {
      int vrow = n * 16 + l15;
      vfp[n][0] = *(const bf16x8*)&vs[cur][vrow * 64 + ((g ^ (vrow & 7)) * 8)];
      vfp[n][1] = *(const bf16x8*)&vs[cur][vrow * 64 + (((4 + g) ^ (vrow & 7)) * 8)];
    }

    // ---- softmax(t): frozen max, exp2, repack -> pbp (for next iter) ----
    if (it == 0) {
      float pm = fmaxf(fmaxf(scT[0][0], scT[0][1]), fmaxf(scT[0][2], scT[0][3]));
#pragma unroll
      for (int tt = 1; tt < 4; tt++)
        pm = fmaxf(pm, fmaxf(fmaxf(scT[tt][0], scT[tt][1]), fmaxf(scT[tt][2], scT[tt][3])));
      pm = fmaxf(pm, __shfl_xor(pm, 16));
      pm = fmaxf(pm, __shfl_xor(pm, 32));
      negms = -pm * SCALE;
    }
    float p[4][4];
#pragma unroll
    for (int tt = 0; tt < 4; tt++)
#pragma unroll
      for (int r = 0; r < 4; r++) p[tt][r] = __builtin_amdgcn_exp2f(fmaf(scT[tt][r], SCALE, negms));
    uint32_t P32[4][2];
#pragma unroll
    for (int tt = 0; tt < 4; tt++)
#pragma unroll
      for (int m = 0; m < 2; m++) P32[tt][m] = cvt_pk_bf16(p[tt][2 * m], p[tt][2 * m + 1]);
#pragma unroll
    for (int t5 = 0; t5 < 2; t5++)
#pragma unroll
      for (int m = 0; m < 2; m++) {
        asm("v_permlane32_swap_b32 %0, %1" : "+v"(P32[2 * t5][m]), "+v"(P32[2 * t5 + 1][m]));
        asm("v_permlane16_swap_b32 %0, %1" : "+v"(P32[2 * t5][m]), "+v"(P32[2 * t5 + 1][m]));
      }
#pragma unroll
    for (int s2 = 0; s2 < 2; s2++) {
      union { uint32_t u[4]; bf16x8 v; } uu;
      uu.u[0] = P32[2 * s2][0];
      uu.u[1] = P32[2 * s2][1];
      uu.u[2] = P32[2 * s2 + 1][0];
      uu.u[3] = P32[2 * s2 + 1][1];
      pbp[s2] = uu.v;
    }

    // deferred V reads must land before next iter's stage overwrites vs[cur]
    asm volatile("s_waitcnt lgkmcnt(0)" ::: "memory");
    __builtin_amdgcn_s_barrier();
  }

  // ---- epilogue: PV(last) ----
  lacc = mfma16(onef, pbp[0], lacc);
  lacc = mfma16(onef, pbp[1], lacc);
#pragma unroll
  for (int n = 0; n < 4; n++) {
    accT[n] = mfma16(vfp[n][0], pbp[0], accT[n]);
    accT[n] = mfma16(vfp[n][1], pbp[1], accT[n]);
  }

  float inv = 1.f / lacc[0];
  int srow = q0 + l15;
#pragma unroll
  for (int n = 0; n < 4; n++) {
    u16x4 o;
    o.x = f2bf(accT[n][0] * inv);
    o.y = f2bf(accT[n][1] * inv);
    o.z = f2bf(accT[n][2] * inv);
    o.w = f2bf(accT[n][3] * inv);
    *(u16x4*)(ctx + ((size_t)srow * BATCH + b) * DMODEL + h * DHEAD + n * 16 + 4 * g) = o;
  }
}

extern "C" void kernel_launch(void* const* d_in, const int* in_sizes, int n_in, void* d_out,
                              int out_size, void* d_ws, size_t ws_size, hipStream_t stream) {
  (void)in_sizes; (void)n_in; (void)out_size; (void)ws_size;
  const float* x    = (const float*)d_in[0];
  const float* wq   = (const float*)d_in[1];
  const float* wk   = (const float*)d_in[2];
  const float* wv   = (const float*)d_in[3];
  const float* wo   = (const float*)d_in[4];
  const float* ln1g = (const float*)d_in[5];
  const float* ln1b = (const float*)d_in[6];
  const float* ln2g = (const float*)d_in[7];
  const float* ln2b = (const float*)d_in[8];
  const float* w1   = (const float*)d_in[9];
  const float* b1   = (const float*)d_in[10];
  const float* w2   = (const float*)d_in[11];
  const float* b2   = (const float*)d_in[12];

  char* ws = (char*)d_ws;
  size_t off = 0;
  auto alloc = [&](size_t bytes) {
    void* p = ws + off;
    off += (bytes + 255) & ~(size_t)255;
    return p;
  };
  u16* yb    = (u16*)alloc((size_t)MROWS * DMODEL * 2);
  u16* wqkvt = (u16*)alloc((size_t)3072 * 1024 * 2);
  u16* wot   = (u16*)alloc((size_t)1024 * 1024 * 2);
  u16* w1t   = (u16*)alloc((size_t)4096 * 1024 * 2);
  u16* w2t   = (u16*)alloc((size_t)1024 * 4096 * 2);
  u16* qkvb  = (u16*)alloc((size_t)MROWS * 3072 * 2);
  u16* vtb   = (u16*)alloc((size_t)BATCH * NHEAD * DHEAD * S_LEN * 2);
  u16* ctxb  = (u16*)alloc((size_t)MROWS * DMODEL * 2);
  float* x1  = (float*)alloc((size_t)MROWS * DMODEL * 4);
  u16* zb    = (u16*)alloc((size_t)MROWS * DMODEL * 2);
  u16* hb    = (u16*)alloc((size_t)MROWS * FFDIM * 2);

  // sublayer 0
  ln_kernel<<<MROWS, 256, 0, stream>>>(x, ln1g, ln1b, yb);
  transpose_all<<<12288, 256, 0, stream>>>(wq, wk, wv, wo, w1, w2, wqkvt, wot, w1t, w2t);

  gemm_bt<0, 128><<<dim3(3072 / 128, 4096 / 128), 256, 0, stream>>>(yb, wqkvt, qkvb, nullptr,
                                                                    nullptr, 4096, 3072, 1024);
  transpose_v<<<dim3(64, 2, 32), 256, 0, stream>>>(qkvb, vtb);
  attn_kernel<<<dim3(32, 32), 256, 0, stream>>>(qkvb, vtb, ctxb);
  gemm_bt8<1><<<dim3(1024 / 64, 4096 / 256), 512, 0, stream>>>(ctxb, wot, x1, nullptr, x, 4096,
                                                               1024, 1024);

  // sublayer 1
  ln_kernel<<<MROWS, 256, 0, stream>>>(x1, ln2g, ln2b, zb);
  gemm_bt<2, 128><<<dim3(32, 32), 256, 0, stream>>>(zb, w1t, hb, b1, nullptr, 4096, 4096, 1024);
  gemm_bt8<3><<<dim3(1024 / 64, 4096 / 256), 512, 0, stream>>>(hb, w2t, d_out, b2, x1, 4096, 1024,
                                                               4096);
}

// Round 12
// 233.492 us; speedup vs baseline: 1.0910x; 1.0910x over previous
//
#include <hip/hip_runtime.h>
#include <hip/hip_bf16.h>
#include <stdint.h>

// Transformer layer: S=2048, B=2, D=1024, H=16, DH=64, FF=4096. fp32 in/out.
// Strategy: fp32 LN/softmax/accum, bf16 MFMA (16x16x32) for all GEMMs.

#define S_LEN 2048
#define BATCH 2
#define DMODEL 1024
#define NHEAD 16
#define DHEAD 64
#define FFDIM 4096
#define MROWS (S_LEN * BATCH)  // 4096 rows, row index = s*B + b

typedef unsigned short u16;
typedef __attribute__((ext_vector_type(8))) __bf16 bf16x8;
typedef __attribute__((ext_vector_type(4))) float f32x4;
typedef __attribute__((ext_vector_type(4))) u16 u16x4;

__device__ inline u16 f2bf(float f) {
  union { float f; unsigned u; } v; v.f = f;
  unsigned r = v.u + 0x7fffu + ((v.u >> 16) & 1u);  // round-to-nearest-even
  return (u16)(r >> 16);
}

__device__ inline f32x4 mfma16(bf16x8 a, bf16x8 b, f32x4 c) {
  return __builtin_amdgcn_mfma_f32_16x16x32_bf16(a, b, c, 0, 0, 0);
}

// async global->LDS, 16B per lane. LDS dest must be wave-uniform base; HW adds lane*16.
__device__ inline void gload_lds16(const u16* g, u16* l) {
  __builtin_amdgcn_global_load_lds(
      (const __attribute__((address_space(1))) unsigned int*)g,
      (__attribute__((address_space(3))) unsigned int*)l, 16, 0, 0);
}

__device__ inline uint32_t cvt_pk_bf16(float lo, float hi) {
  uint32_t r;
  asm("v_cvt_pk_bf16_f32 %0, %1, %2" : "=v"(r) : "v"(lo), "v"(hi));
  return r;
}

// ---------------- LayerNorm: fp32 in -> bf16 out ----------------
__global__ __launch_bounds__(256) void ln_kernel(const float* __restrict__ x,
                                                 const float* __restrict__ gam,
                                                 const float* __restrict__ bet,
                                                 u16* __restrict__ out) {
  int row = blockIdx.x;
  int tid = threadIdx.x;
  const float4* xr = (const float4*)(x + (size_t)row * DMODEL);
  float4 v = xr[tid];
  float s = v.x + v.y + v.z + v.w;
  float ss = v.x * v.x + v.y * v.y + v.z * v.z + v.w * v.w;
#pragma unroll
  for (int m = 1; m < 64; m <<= 1) {
    s += __shfl_xor(s, m);
    ss += __shfl_xor(ss, m);
  }
  __shared__ float red[8];
  int w = tid >> 6, lane = tid & 63;
  if (lane == 0) { red[w] = s; red[4 + w] = ss; }
  __syncthreads();
  s = red[0] + red[1] + red[2] + red[3];
  ss = red[4] + red[5] + red[6] + red[7];
  float mu = s * (1.f / DMODEL);
  float var = ss * (1.f / DMODEL) - mu * mu;
  float rstd = rsqrtf(var + 1e-5f);
  float4 gv = ((const float4*)gam)[tid];
  float4 bv = ((const float4*)bet)[tid];
  u16x4 o;
  o.x = f2bf((v.x - mu) * rstd * gv.x + bv.x);
  o.y = f2bf((v.y - mu) * rstd * gv.y + bv.y);
  o.z = f2bf((v.z - mu) * rstd * gv.z + bv.z);
  o.w = f2bf((v.w - mu) * rstd * gv.w + bv.w);
  *(u16x4*)(out + (size_t)row * DMODEL + tid * 4) = o;
}

// ---------------- fused weight transpose-cast: all 6 weights in ONE launch ----------------
__global__ __launch_bounds__(256) void transpose_all(const float* __restrict__ wq,
                                                     const float* __restrict__ wk,
                                                     const float* __restrict__ wv,
                                                     const float* __restrict__ wo,
                                                     const float* __restrict__ w1,
                                                     const float* __restrict__ w2,
                                                     u16* __restrict__ wqkvt, u16* __restrict__ wot,
                                                     u16* __restrict__ w1t, u16* __restrict__ w2t) {
  int idx = blockIdx.x;
  const float* in;
  u16* out;
  int R, C;
  if (idx < 3072) {
    int which = idx >> 10;
    in = (which == 0) ? wq : (which == 1) ? wk : wv;
    out = wqkvt + (size_t)which * 1024 * 1024;
    R = 1024; C = 1024;
    idx &= 1023;
  } else if (idx < 4096) {
    in = wo; out = wot; R = 1024; C = 1024; idx -= 3072;
  } else if (idx < 8192) {
    in = w1; out = w1t; R = 1024; C = 4096; idx -= 4096;
  } else {
    in = w2; out = w2t; R = 4096; C = 1024; idx -= 8192;
  }
  int ntx = C >> 5;
  int tc = idx % ntx, tr = idx / ntx;
  int c0 = tc * 32, r0 = tr * 32;
  __shared__ u16 tile[32][33];
  int tx = threadIdx.x & 31, grp = threadIdx.x >> 5;
#pragma unroll
  for (int i = 0; i < 4; i++) {
    int r = grp * 4 + i;
    tile[r][tx] = f2bf(in[(size_t)(r0 + r) * C + c0 + tx]);
  }
  __syncthreads();
#pragma unroll
  for (int i = 0; i < 4; i++) {
    int rr = grp * 4 + i;
    out[(size_t)(c0 + rr) * R + r0 + tx] = tile[tx][rr];
  }
}

// ---------------- V slice of qkv -> Vt[bh][dh][s] ----------------
__global__ __launch_bounds__(256) void transpose_v(const u16* __restrict__ qkv,
                                                   u16* __restrict__ vt) {
  __shared__ u16 tile[32][33];
  int bh = blockIdx.z;
  int b = bh >> 4;
  int s0 = blockIdx.x * 32, d0 = blockIdx.y * 32;
  int h = bh & 15;
  int tx = threadIdx.x & 31, grp = threadIdx.x >> 5;
#pragma unroll
  for (int i = 0; i < 4; i++) {
    int sl = grp * 4 + i;
    tile[sl][tx] = qkv[(size_t)((s0 + sl) * BATCH + b) * 3072 + 2048 + h * DHEAD + d0 + tx];
  }
  __syncthreads();
#pragma unroll
  for (int i = 0; i < 4; i++) {
    int dl = grp * 4 + i;
    vt[((size_t)bh * DHEAD + d0 + dl) * S_LEN + s0 + tx] = tile[tx][dl];
  }
}

// ---------------- GEMM (R5/R8-proven, FROZEN): BK=64, XOR-swizzled LDS, counted-vmcnt 2-phase ----
// C[M][N] = A[M][K](bf16) @ Bt[N][K](bf16)^T.  BM=128, BN in {128,64}, 4 waves.
// MODE 0: bf16 out.  MODE 1: fp32 out = acc + res.
// MODE 2: bf16 out = relu(acc + bias).  MODE 3: fp32 out = acc + bias + res.
template <int MODE, int BN>
__global__ __launch_bounds__(256) void gemm_bt(const u16* __restrict__ A,
                                               const u16* __restrict__ Bt, void* __restrict__ Cout,
                                               const float* __restrict__ bias,
                                               const float* __restrict__ res, int M, int N, int K) {
  __shared__ __align__(16) u16 As[2][128 * 64];
  __shared__ __align__(16) u16 Bs[2][BN * 64];
  constexpr int NLOADS = 4 + BN / 32;

  int nwg = gridDim.x * gridDim.y;
  int f = blockIdx.y * gridDim.x + blockIdx.x;
  int nf = ((nwg & 7) == 0) ? ((f & 7) * (nwg >> 3) + (f >> 3)) : f;
  int bx = nf % gridDim.x, by = nf / gridDim.x;

  int bm0 = by * 128, bn0 = bx * BN;
  int tid = threadIdx.x, w = tid >> 6, lane = tid & 63;
  int g = lane >> 4, l15 = lane & 15;
  int lr = lane >> 3, ch = lane & 7;
  int srcch = (ch ^ lr) * 8;  // pre-swizzled 16B-chunk column offset (rule 21c)
  int wm = (w >> 1) * 64, wn = (w & 1) * (BN / 2);
  const int NJ = BN / 32;

  f32x4 acc[4][NJ];
#pragma unroll
  for (int i = 0; i < 4; i++)
#pragma unroll
    for (int j = 0; j < NJ; j++) {
      f32x4 z = {0.f, 0.f, 0.f, 0.f};
      acc[i][j] = z;
    }

  auto stage = [&](int k0, int buf) {
#pragma unroll
    for (int rd = 0; rd < 4; rd++) {
      int rb = (rd * 4 + w) * 8;  // lane's row = rb + lr; row&7 == lr
      gload_lds16(A + (size_t)(bm0 + rb + lr) * K + k0 + srcch, &As[buf][rb * 64]);
    }
#pragma unroll
    for (int rd = 0; rd < BN / 32; rd++) {
      int rb = (rd * 4 + w) * 8;
      gload_lds16(Bt + (size_t)(bn0 + rb + lr) * K + k0 + srcch, &Bs[buf][rb * 64]);
    }
  };

  int nkt = K >> 6;
  stage(0, 0);
  asm volatile("s_waitcnt vmcnt(0)" ::: "memory");
  __builtin_amdgcn_s_barrier();

  for (int kt = 0; kt < nkt; ++kt) {
    int cur = kt & 1;
    if (kt + 1 < nkt) {
      stage((kt + 1) << 6, cur ^ 1);
      asm volatile("s_waitcnt vmcnt(%0)" ::"n"(NLOADS) : "memory");
    } else {
      asm volatile("s_waitcnt vmcnt(0)" ::: "memory");
    }
    __builtin_amdgcn_s_barrier();
#pragma unroll
    for (int kk = 0; kk < 2; kk++) {
      bf16x8 af[4], bfr[NJ];
#pragma unroll
      for (int i = 0; i < 4; i++) {
        int row = wm + i * 16 + l15;
        af[i] = *(const bf16x8*)&As[cur][row * 64 + (((kk * 4 + g) ^ (row & 7)) * 8)];
      }
#pragma unroll
      for (int j = 0; j < NJ; j++) {
        int row = wn + j * 16 + l15;
        bfr[j] = *(const bf16x8*)&Bs[cur][row * 64 + (((kk * 4 + g) ^ (row & 7)) * 8)];
      }
#pragma unroll
      for (int i = 0; i < 4; i++)
#pragma unroll
        for (int j = 0; j < NJ; j++) acc[i][j] = mfma16(af[i], bfr[j], acc[i][j]);
    }
    __builtin_amdgcn_s_barrier();
  }

  // epilogue: D layout col = lane&15, row = 4*(lane>>4) + r
#pragma unroll
  for (int i = 0; i < 4; i++)
#pragma unroll
    for (int j = 0; j < NJ; j++) {
      int col = bn0 + wn + j * 16 + l15;
      float bval = (MODE == 2 || MODE == 3) ? bias[col] : 0.f;
#pragma unroll
      for (int r = 0; r < 4; r++) {
        int row = bm0 + wm + i * 16 + g * 4 + r;
        size_t idx = (size_t)row * N + col;
        float vacc = acc[i][j][r] + bval;
        if (MODE == 0)
          ((u16*)Cout)[idx] = f2bf(vacc);
        else if (MODE == 1)
          ((float*)Cout)[idx] = vacc + res[idx];
        else if (MODE == 2)
          ((u16*)Cout)[idx] = f2bf(fmaxf(vacc, 0.f));
        else
          ((float*)Cout)[idx] = vacc + res[idx];
      }
    }
}

// ---------------- flash attention v8: deferred-PV + 8-wave blocks for TLP ----------------
// grid (S/128, B*H) XCD-chunked, 512 thr = 8 waves; wave owns 16 q rows (QBLK=128).
// Same wave-level algebra as v7 (swapped QK, frozen max, ones-MFMA denominator,
// in-register P repack, deferred PV). 8 waves share the same 32KB K/V LDS tiles ->
// staging per wave halves (1 K + 1 V gload_lds of 8 rows); 2 blocks/CU x 8 waves
// = 16 waves/CU (was 10) to hide the exp2/repack VALU chain.
__global__ __launch_bounds__(512) void attn_kernel(const u16* __restrict__ qkv,
                                                   const u16* __restrict__ vt,
                                                   u16* __restrict__ ctx) {
  int nwg = gridDim.x * gridDim.y;  // 512
  int f = blockIdx.y * gridDim.x + blockIdx.x;
  int nf = (f & 7) * (nwg >> 3) + (f >> 3);
  int qblk = nf % gridDim.x, bh = nf / gridDim.x;
  int b = bh >> 4, h = bh & 15;
  int tid = threadIdx.x, w = tid >> 6, lane = tid & 63;
  int g = lane >> 4, l15 = lane & 15;
  int lr = lane >> 3, ch = lane & 7;
  int q0 = qblk * 128 + w * 16;
  const float SCALE = 0.125f * 1.44269504f;  // 1/sqrt(64) * log2(e)

  __shared__ __align__(16) u16 ks[2][64 * 64];
  __shared__ __align__(16) u16 vs[2][64 * 64];

  bf16x8 qf0, qf1;
  {
    const u16* qp = qkv + ((size_t)(q0 + l15) * BATCH + b) * 3072 + h * DHEAD;
    qf0 = *(const bf16x8*)(qp + g * 8);
    qf1 = *(const bf16x8*)(qp + 32 + g * 8);
  }
  bf16x8 onef;
  {
    union { u16 u[8]; bf16x8 v; } ou;
#pragma unroll
    for (int i = 0; i < 8; i++) ou.u[i] = 0x3F80;  // bf16 1.0
    onef = ou.v;
  }

  f32x4 accT[4];
#pragma unroll
  for (int n = 0; n < 4; n++) {
    f32x4 z = {0.f, 0.f, 0.f, 0.f};
    accT[n] = z;
  }
  f32x4 lacc = {0.f, 0.f, 0.f, 0.f};  // denominator (all rows equal)
  float negms = 0.f;                  // = -max_tile0 * SCALE, set at it==0
  bf16x8 pbp[2];                      // P frags of previous tile
  bf16x8 vfp[4][2];                   // V frags of previous tile

  // 8 waves cover 64 rows: wave w stages rows w*8..w*8+7 (1 K + 1 V load)
  auto stage = [&](int t0, int buf) {
    int rb = w * 8;
    int row = rb + lr;  // row & 7 == lr
    const u16* ksrc =
        qkv + ((size_t)(t0 + row) * BATCH + b) * 3072 + 1024 + h * DHEAD + (ch ^ lr) * 8;
    gload_lds16(ksrc, &ks[buf][rb * 64]);
    const u16* vsrc = vt + ((size_t)bh * DHEAD + row) * S_LEN + t0 + (ch ^ lr) * 8;
    gload_lds16(vsrc, &vs[buf][rb * 64]);
  };

  stage(0, 0);
  asm volatile("s_waitcnt vmcnt(0)" ::: "memory");
  __builtin_amdgcn_s_barrier();

  for (int it = 0; it < S_LEN / 64; ++it) {
    int cur = it & 1;
    if (it + 1 < S_LEN / 64) {
      stage((it + 1) * 64, cur ^ 1);
      asm volatile("s_waitcnt vmcnt(2)" ::: "memory");  // prev iter's 2 loads landed
    } else {
      asm volatile("s_waitcnt vmcnt(0)" ::: "memory");
    }
    __builtin_amdgcn_s_barrier();

    // ---- QK^T(t) (swapped): scT[tt][r] = S_raw^T[16tt+4g+r][q0+l15] ----
    f32x4 scT[4];
#pragma unroll
    for (int tt = 0; tt < 4; tt++) {
      int row = tt * 16 + l15;
      bf16x8 kf0 = *(const bf16x8*)&ks[cur][row * 64 + ((g ^ (row & 7)) * 8)];
      bf16x8 kf1 = *(const bf16x8*)&ks[cur][row * 64 + (((4 + g) ^ (row & 7)) * 8)];
      f32x4 z = {0.f, 0.f, 0.f, 0.f};
      __builtin_amdgcn_s_setprio(1);
      z = mfma16(kf0, qf0, z);
      z = mfma16(kf1, qf1, z);
      __builtin_amdgcn_s_setprio(0);
      scT[tt] = z;
    }

    // ---- PV(t-1) + denominator: pure-register MFMA, independent of softmax(t) ----
    if (it > 0) {
      __builtin_amdgcn_s_setprio(1);
      lacc = mfma16(onef, pbp[0], lacc);
      lacc = mfma16(onef, pbp[1], lacc);
#pragma unroll
      for (int n = 0; n < 4; n++) {
        accT[n] = mfma16(vfp[n][0], pbp[0], accT[n]);
        accT[n] = mfma16(vfp[n][1], pbp[1], accT[n]);
      }
      __builtin_amdgcn_s_setprio(0);
    }

    // ---- load V(t) frags (consumed next iter); overlaps softmax VALU below ----
#pragma unroll
    for (int n = 0; n < 4; n++) {
      int vrow = n * 16 + l15;
      vfp[n][0] = *(const bf16x8*)&vs[cur][vrow * 64 + ((g ^ (vrow & 7)) * 8)];
      vfp[n][1] = *(const bf16x8*)&vs[cur][vrow * 64 + (((4 + g) ^ (vrow & 7)) * 8)];
    }

    // ---- softmax(t): frozen max, exp2, repack -> pbp (for next iter) ----
    if (it == 0) {
      float pm = fmaxf(fmaxf(scT[0][0], scT[0][1]), fmaxf(scT[0][2], scT[0][3]));
#pragma unroll
      for (int tt = 1; tt < 4; tt++)
        pm = fmaxf(pm, fmaxf(fmaxf(scT[tt][0], scT[tt][1]), fmaxf(scT[tt][2], scT[tt][3])));
      pm = fmaxf(pm, __shfl_xor(pm, 16));
      pm = fmaxf(pm, __shfl_xor(pm, 32));
      negms = -pm * SCALE;
    }
    float p[4][4];
#pragma unroll
    for (int tt = 0; tt < 4; tt++)
#pragma unroll
      for (int r = 0; r < 4; r++) p[tt][r] = __builtin_amdgcn_exp2f(fmaf(scT[tt][r], SCALE, negms));
    uint32_t P32[4][2];
#pragma unroll
    for (int tt = 0; tt < 4; tt++)
#pragma unroll
      for (int m = 0; m < 2; m++) P32[tt][m] = cvt_pk_bf16(p[tt][2 * m], p[tt][2 * m + 1]);
#pragma unroll
    for (int t5 = 0; t5 < 2; t5++)
#pragma unroll
      for (int m = 0; m < 2; m++) {
        asm("v_permlane32_swap_b32 %0, %1" : "+v"(P32[2 * t5][m]), "+v"(P32[2 * t5 + 1][m]));
        asm("v_permlane16_swap_b32 %0, %1" : "+v"(P32[2 * t5][m]), "+v"(P32[2 * t5 + 1][m]));
      }
#pragma unroll
    for (int s2 = 0; s2 < 2; s2++) {
      union { uint32_t u[4]; bf16x8 v; } uu;
      uu.u[0] = P32[2 * s2][0];
      uu.u[1] = P32[2 * s2][1];
      uu.u[2] = P32[2 * s2 + 1][0];
      uu.u[3] = P32[2 * s2 + 1][1];
      pbp[s2] = uu.v;
    }

    // deferred V reads must land before next iter's stage overwrites vs[cur]
    asm volatile("s_waitcnt lgkmcnt(0)" ::: "memory");
    __builtin_amdgcn_s_barrier();
  }

  // ---- epilogue: PV(last) ----
  lacc = mfma16(onef, pbp[0], lacc);
  lacc = mfma16(onef, pbp[1], lacc);
#pragma unroll
  for (int n = 0; n < 4; n++) {
    accT[n] = mfma16(vfp[n][0], pbp[0], accT[n]);
    accT[n] = mfma16(vfp[n][1], pbp[1], accT[n]);
  }

  float inv = 1.f / lacc[0];
  int srow = q0 + l15;
#pragma unroll
  for (int n = 0; n < 4; n++) {
    u16x4 o;
    o.x = f2bf(accT[n][0] * inv);
    o.y = f2bf(accT[n][1] * inv);
    o.z = f2bf(accT[n][2] * inv);
    o.w = f2bf(accT[n][3] * inv);
    *(u16x4*)(ctx + ((size_t)srow * BATCH + b) * DMODEL + h * DHEAD + n * 16 + 4 * g) = o;
  }
}

extern "C" void kernel_launch(void* const* d_in, const int* in_sizes, int n_in, void* d_out,
                              int out_size, void* d_ws, size_t ws_size, hipStream_t stream) {
  (void)in_sizes; (void)n_in; (void)out_size; (void)ws_size;
  const float* x    = (const float*)d_in[0];
  const float* wq   = (const float*)d_in[1];
  const float* wk   = (const float*)d_in[2];
  const float* wv   = (const float*)d_in[3];
  const float* wo   = (const float*)d_in[4];
  const float* ln1g = (const float*)d_in[5];
  const float* ln1b = (const float*)d_in[6];
  const float* ln2g = (const float*)d_in[7];
  const float* ln2b = (const float*)d_in[8];
  const float* w1   = (const float*)d_in[9];
  const float* b1   = (const float*)d_in[10];
  const float* w2   = (const float*)d_in[11];
  const float* b2   = (const float*)d_in[12];

  char* ws = (char*)d_ws;
  size_t off = 0;
  auto alloc = [&](size_t bytes) {
    void* p = ws + off;
    off += (bytes + 255) & ~(size_t)255;
    return p;
  };
  u16* yb    = (u16*)alloc((size_t)MROWS * DMODEL * 2);
  u16* wqkvt = (u16*)alloc((size_t)3072 * 1024 * 2);
  u16* wot   = (u16*)alloc((size_t)1024 * 1024 * 2);
  u16* w1t   = (u16*)alloc((size_t)4096 * 1024 * 2);
  u16* w2t   = (u16*)alloc((size_t)1024 * 4096 * 2);
  u16* qkvb  = (u16*)alloc((size_t)MROWS * 3072 * 2);
  u16* vtb   = (u16*)alloc((size_t)BATCH * NHEAD * DHEAD * S_LEN * 2);
  u16* ctxb  = (u16*)alloc((size_t)MROWS * DMODEL * 2);
  float* x1  = (float*)alloc((size_t)MROWS * DMODEL * 4);
  u16* zb    = (u16*)alloc((size_t)MROWS * DMODEL * 2);
  u16* hb    = (u16*)alloc((size_t)MROWS * FFDIM * 2);

  // sublayer 0
  ln_kernel<<<MROWS, 256, 0, stream>>>(x, ln1g, ln1b, yb);
  transpose_all<<<12288, 256, 0, stream>>>(wq, wk, wv, wo, w1, w2, wqkvt, wot, w1t, w2t);

  gemm_bt<0, 128><<<dim3(3072 / 128, 4096 / 128), 256, 0, stream>>>(yb, wqkvt, qkvb, nullptr,
                                                                    nullptr, 4096, 3072, 1024);
  transpose_v<<<dim3(64, 2, 32), 256, 0, stream>>>(qkvb, vtb);
  attn_kernel<<<dim3(16, 32), 512, 0, stream>>>(qkvb, vtb, ctxb);
  gemm_bt<1, 64><<<dim3(16, 32), 256, 0, stream>>>(ctxb, wot, x1, nullptr, x, 4096, 1024, 1024);

  // sublayer 1
  ln_kernel<<<MROWS, 256, 0, stream>>>(x1, ln2g, ln2b, zb);
  gemm_bt<2, 128><<<dim3(32, 32), 256, 0, stream>>>(zb, w1t, hb, b1, nullptr, 4096, 4096, 1024);
  gemm_bt<3, 64><<<dim3(16, 32), 256, 0, stream>>>(hb, w2t, d_out, b2, x1, 4096, 1024, 4096);
}

// Round 13
// 232.263 us; speedup vs baseline: 1.0968x; 1.0053x over previous
//
#include <hip/hip_runtime.h>
#include <hip/hip_bf16.h>
#include <stdint.h>

// Transformer layer: S=2048, B=2, D=1024, H=16, DH=64, FF=4096. fp32 in/out.
// Strategy: fp32 LN/softmax/accum, bf16 MFMA (16x16x32) for all GEMMs.
// R13: x1 residual stored bf16 (halves Wo-write / LN2-read / FFN2-res traffic).

#define S_LEN 2048
#define BATCH 2
#define DMODEL 1024
#define NHEAD 16
#define DHEAD 64
#define FFDIM 4096
#define MROWS (S_LEN * BATCH)  // 4096 rows, row index = s*B + b

typedef unsigned short u16;
typedef __attribute__((ext_vector_type(8))) __bf16 bf16x8;
typedef __attribute__((ext_vector_type(4))) float f32x4;
typedef __attribute__((ext_vector_type(4))) u16 u16x4;

__device__ inline u16 f2bf(float f) {
  union { float f; unsigned u; } v; v.f = f;
  unsigned r = v.u + 0x7fffu + ((v.u >> 16) & 1u);  // round-to-nearest-even
  return (u16)(r >> 16);
}

__device__ inline float bf2f(u16 u) {
  union { unsigned u; float f; } v;
  v.u = ((unsigned)u) << 16;
  return v.f;
}

__device__ inline f32x4 mfma16(bf16x8 a, bf16x8 b, f32x4 c) {
  return __builtin_amdgcn_mfma_f32_16x16x32_bf16(a, b, c, 0, 0, 0);
}

// async global->LDS, 16B per lane. LDS dest must be wave-uniform base; HW adds lane*16.
__device__ inline void gload_lds16(const u16* g, u16* l) {
  __builtin_amdgcn_global_load_lds(
      (const __attribute__((address_space(1))) unsigned int*)g,
      (__attribute__((address_space(3))) unsigned int*)l, 16, 0, 0);
}

__device__ inline uint32_t cvt_pk_bf16(float lo, float hi) {
  uint32_t r;
  asm("v_cvt_pk_bf16_f32 %0, %1, %2" : "=v"(r) : "v"(lo), "v"(hi));
  return r;
}

// ---------------- LayerNorm: fp32 in -> bf16 out ----------------
__global__ __launch_bounds__(256) void ln_kernel(const float* __restrict__ x,
                                                 const float* __restrict__ gam,
                                                 const float* __restrict__ bet,
                                                 u16* __restrict__ out) {
  int row = blockIdx.x;
  int tid = threadIdx.x;
  const float4* xr = (const float4*)(x + (size_t)row * DMODEL);
  float4 v = xr[tid];
  float s = v.x + v.y + v.z + v.w;
  float ss = v.x * v.x + v.y * v.y + v.z * v.z + v.w * v.w;
#pragma unroll
  for (int m = 1; m < 64; m <<= 1) {
    s += __shfl_xor(s, m);
    ss += __shfl_xor(ss, m);
  }
  __shared__ float red[8];
  int w = tid >> 6, lane = tid & 63;
  if (lane == 0) { red[w] = s; red[4 + w] = ss; }
  __syncthreads();
  s = red[0] + red[1] + red[2] + red[3];
  ss = red[4] + red[5] + red[6] + red[7];
  float mu = s * (1.f / DMODEL);
  float var = ss * (1.f / DMODEL) - mu * mu;
  float rstd = rsqrtf(var + 1e-5f);
  float4 gv = ((const float4*)gam)[tid];
  float4 bv = ((const float4*)bet)[tid];
  u16x4 o;
  o.x = f2bf((v.x - mu) * rstd * gv.x + bv.x);
  o.y = f2bf((v.y - mu) * rstd * gv.y + bv.y);
  o.z = f2bf((v.z - mu) * rstd * gv.z + bv.z);
  o.w = f2bf((v.w - mu) * rstd * gv.w + bv.w);
  *(u16x4*)(out + (size_t)row * DMODEL + tid * 4) = o;
}

// ---------------- LayerNorm: bf16 in -> bf16 out (for LN2 on bf16 x1) ----------------
__global__ __launch_bounds__(256) void ln_kernel_b(const u16* __restrict__ x,
                                                   const float* __restrict__ gam,
                                                   const float* __restrict__ bet,
                                                   u16* __restrict__ out) {
  int row = blockIdx.x;
  int tid = threadIdx.x;
  u16x4 uv = *(const u16x4*)(x + (size_t)row * DMODEL + tid * 4);
  float4 v;
  v.x = bf2f(uv.x); v.y = bf2f(uv.y); v.z = bf2f(uv.z); v.w = bf2f(uv.w);
  float s = v.x + v.y + v.z + v.w;
  float ss = v.x * v.x + v.y * v.y + v.z * v.z + v.w * v.w;
#pragma unroll
  for (int m = 1; m < 64; m <<= 1) {
    s += __shfl_xor(s, m);
    ss += __shfl_xor(ss, m);
  }
  __shared__ float red[8];
  int w = tid >> 6, lane = tid & 63;
  if (lane == 0) { red[w] = s; red[4 + w] = ss; }
  __syncthreads();
  s = red[0] + red[1] + red[2] + red[3];
  ss = red[4] + red[5] + red[6] + red[7];
  float mu = s * (1.f / DMODEL);
  float var = ss * (1.f / DMODEL) - mu * mu;
  float rstd = rsqrtf(var + 1e-5f);
  float4 gv = ((const float4*)gam)[tid];
  float4 bv = ((const float4*)bet)[tid];
  u16x4 o;
  o.x = f2bf((v.x - mu) * rstd * gv.x + bv.x);
  o.y = f2bf((v.y - mu) * rstd * gv.y + bv.y);
  o.z = f2bf((v.z - mu) * rstd * gv.z + bv.z);
  o.w = f2bf((v.w - mu) * rstd * gv.w + bv.w);
  *(u16x4*)(out + (size_t)row * DMODEL + tid * 4) = o;
}

// ---------------- fused weight transpose-cast: all 6 weights in ONE launch ----------------
__global__ __launch_bounds__(256) void transpose_all(const float* __restrict__ wq,
                                                     const float* __restrict__ wk,
                                                     const float* __restrict__ wv,
                                                     const float* __restrict__ wo,
                                                     const float* __restrict__ w1,
                                                     const float* __restrict__ w2,
                                                     u16* __restrict__ wqkvt, u16* __restrict__ wot,
                                                     u16* __restrict__ w1t, u16* __restrict__ w2t) {
  int idx = blockIdx.x;
  const float* in;
  u16* out;
  int R, C;
  if (idx < 3072) {
    int which = idx >> 10;
    in = (which == 0) ? wq : (which == 1) ? wk : wv;
    out = wqkvt + (size_t)which * 1024 * 1024;
    R = 1024; C = 1024;
    idx &= 1023;
  } else if (idx < 4096) {
    in = wo; out = wot; R = 1024; C = 1024; idx -= 3072;
  } else if (idx < 8192) {
    in = w1; out = w1t; R = 1024; C = 4096; idx -= 4096;
  } else {
    in = w2; out = w2t; R = 4096; C = 1024; idx -= 8192;
  }
  int ntx = C >> 5;
  int tc = idx % ntx, tr = idx / ntx;
  int c0 = tc * 32, r0 = tr * 32;
  __shared__ u16 tile[32][33];
  int tx = threadIdx.x & 31, grp = threadIdx.x >> 5;
#pragma unroll
  for (int i = 0; i < 4; i++) {
    int r = grp * 4 + i;
    tile[r][tx] = f2bf(in[(size_t)(r0 + r) * C + c0 + tx]);
  }
  __syncthreads();
#pragma unroll
  for (int i = 0; i < 4; i++) {
    int rr = grp * 4 + i;
    out[(size_t)(c0 + rr) * R + r0 + tx] = tile[tx][rr];
  }
}

// ---------------- V slice of qkv -> Vt[bh][dh][s] ----------------
__global__ __launch_bounds__(256) void transpose_v(const u16* __restrict__ qkv,
                                                   u16* __restrict__ vt) {
  __shared__ u16 tile[32][33];
  int bh = blockIdx.z;
  int b = bh >> 4;
  int s0 = blockIdx.x * 32, d0 = blockIdx.y * 32;
  int h = bh & 15;
  int tx = threadIdx.x & 31, grp = threadIdx.x >> 5;
#pragma unroll
  for (int i = 0; i < 4; i++) {
    int sl = grp * 4 + i;
    tile[sl][tx] = qkv[(size_t)((s0 + sl) * BATCH + b) * 3072 + 2048 + h * DHEAD + d0 + tx];
  }
  __syncthreads();
#pragma unroll
  for (int i = 0; i < 4; i++) {
    int dl = grp * 4 + i;
    vt[((size_t)bh * DHEAD + d0 + dl) * S_LEN + s0 + tx] = tile[tx][dl];
  }
}

// ---------------- GEMM (R5/R8-proven, FROZEN): BK=64, XOR-swizzled LDS, counted-vmcnt 2-phase ----
// C[M][N] = A[M][K](bf16) @ Bt[N][K](bf16)^T.  BM=128, BN in {128,64}, 4 waves.
// MODE 0: bf16 out.                MODE 2: bf16 out = relu(acc + bias).
// MODE 5: bf16 out = acc + fp32 res.   MODE 6: fp32 out = acc + bias + bf16 res.
template <int MODE, int BN>
__global__ __launch_bounds__(256) void gemm_bt(const u16* __restrict__ A,
                                               const u16* __restrict__ Bt, void* __restrict__ Cout,
                                               const float* __restrict__ bias,
                                               const void* __restrict__ res, int M, int N, int K) {
  __shared__ __align__(16) u16 As[2][128 * 64];
  __shared__ __align__(16) u16 Bs[2][BN * 64];
  constexpr int NLOADS = 4 + BN / 32;

  int nwg = gridDim.x * gridDim.y;
  int f = blockIdx.y * gridDim.x + blockIdx.x;
  int nf = ((nwg & 7) == 0) ? ((f & 7) * (nwg >> 3) + (f >> 3)) : f;
  int bx = nf % gridDim.x, by = nf / gridDim.x;

  int bm0 = by * 128, bn0 = bx * BN;
  int tid = threadIdx.x, w = tid >> 6, lane = tid & 63;
  int g = lane >> 4, l15 = lane & 15;
  int lr = lane >> 3, ch = lane & 7;
  int srcch = (ch ^ lr) * 8;  // pre-swizzled 16B-chunk column offset (rule 21c)
  int wm = (w >> 1) * 64, wn = (w & 1) * (BN / 2);
  const int NJ = BN / 32;

  f32x4 acc[4][NJ];
#pragma unroll
  for (int i = 0; i < 4; i++)
#pragma unroll
    for (int j = 0; j < NJ; j++) {
      f32x4 z = {0.f, 0.f, 0.f, 0.f};
      acc[i][j] = z;
    }

  auto stage = [&](int k0, int buf) {
#pragma unroll
    for (int rd = 0; rd < 4; rd++) {
      int rb = (rd * 4 + w) * 8;  // lane's row = rb + lr; row&7 == lr
      gload_lds16(A + (size_t)(bm0 + rb + lr) * K + k0 + srcch, &As[buf][rb * 64]);
    }
#pragma unroll
    for (int rd = 0; rd < BN / 32; rd++) {
      int rb = (rd * 4 + w) * 8;
      gload_lds16(Bt + (size_t)(bn0 + rb + lr) * K + k0 + srcch, &Bs[buf][rb * 64]);
    }
  };

  int nkt = K >> 6;
  stage(0, 0);
  asm volatile("s_waitcnt vmcnt(0)" ::: "memory");
  __builtin_amdgcn_s_barrier();

  for (int kt = 0; kt < nkt; ++kt) {
    int cur = kt & 1;
    if (kt + 1 < nkt) {
      stage((kt + 1) << 6, cur ^ 1);
      asm volatile("s_waitcnt vmcnt(%0)" ::"n"(NLOADS) : "memory");
    } else {
      asm volatile("s_waitcnt vmcnt(0)" ::: "memory");
    }
    __builtin_amdgcn_s_barrier();
#pragma unroll
    for (int kk = 0; kk < 2; kk++) {
      bf16x8 af[4], bfr[NJ];
#pragma unroll
      for (int i = 0; i < 4; i++) {
        int row = wm + i * 16 + l15;
        af[i] = *(const bf16x8*)&As[cur][row * 64 + (((kk * 4 + g) ^ (row & 7)) * 8)];
      }
#pragma unroll
      for (int j = 0; j < NJ; j++) {
        int row = wn + j * 16 + l15;
        bfr[j] = *(const bf16x8*)&Bs[cur][row * 64 + (((kk * 4 + g) ^ (row & 7)) * 8)];
      }
#pragma unroll
      for (int i = 0; i < 4; i++)
#pragma unroll
        for (int j = 0; j < NJ; j++) acc[i][j] = mfma16(af[i], bfr[j], acc[i][j]);
    }
    __builtin_amdgcn_s_barrier();
  }

  // epilogue: D layout col = lane&15, row = 4*(lane>>4) + r
#pragma unroll
  for (int i = 0; i < 4; i++)
#pragma unroll
    for (int j = 0; j < NJ; j++) {
      int col = bn0 + wn + j * 16 + l15;
      float bval = (MODE == 2 || MODE == 6) ? bias[col] : 0.f;
#pragma unroll
      for (int r = 0; r < 4; r++) {
        int row = bm0 + wm + i * 16 + g * 4 + r;
        size_t idx = (size_t)row * N + col;
        float vacc = acc[i][j][r] + bval;
        if (MODE == 0)
          ((u16*)Cout)[idx] = f2bf(vacc);
        else if (MODE == 2)
          ((u16*)Cout)[idx] = f2bf(fmaxf(vacc, 0.f));
        else if (MODE == 5)
          ((u16*)Cout)[idx] = f2bf(vacc + ((const float*)res)[idx]);
        else if (MODE == 6)
          ((float*)Cout)[idx] = vacc + bf2f(((const u16*)res)[idx]);
      }
    }
}

// ---------------- flash attention v8 (FROZEN): deferred-PV + 8-wave blocks ----------------
// grid (S/128, B*H) XCD-chunked, 512 thr = 8 waves; wave owns 16 q rows (QBLK=128).
// Swapped QK, frozen max, ones-MFMA denominator, in-register P repack, deferred PV.
__global__ __launch_bounds__(512) void attn_kernel(const u16* __restrict__ qkv,
                                                   const u16* __restrict__ vt,
                                                   u16* __restrict__ ctx) {
  int nwg = gridDim.x * gridDim.y;  // 512
  int f = blockIdx.y * gridDim.x + blockIdx.x;
  int nf = (f & 7) * (nwg >> 3) + (f >> 3);
  int qblk = nf % gridDim.x, bh = nf / gridDim.x;
  int b = bh >> 4, h = bh & 15;
  int tid = threadIdx.x, w = tid >> 6, lane = tid & 63;
  int g = lane >> 4, l15 = lane & 15;
  int lr = lane >> 3, ch = lane & 7;
  int q0 = qblk * 128 + w * 16;
  const float SCALE = 0.125f * 1.44269504f;  // 1/sqrt(64) * log2(e)

  __shared__ __align__(16) u16 ks[2][64 * 64];
  __shared__ __align__(16) u16 vs[2][64 * 64];

  bf16x8 qf0, qf1;
  {
    const u16* qp = qkv + ((size_t)(q0 + l15) * BATCH + b) * 3072 + h * DHEAD;
    qf0 = *(const bf16x8*)(qp + g * 8);
    qf1 = *(const bf16x8*)(qp + 32 + g * 8);
  }
  bf16x8 onef;
  {
    union { u16 u[8]; bf16x8 v; } ou;
#pragma unroll
    for (int i = 0; i < 8; i++) ou.u[i] = 0x3F80;  // bf16 1.0
    onef = ou.v;
  }

  f32x4 accT[4];
#pragma unroll
  for (int n = 0; n < 4; n++) {
    f32x4 z = {0.f, 0.f, 0.f, 0.f};
    accT[n] = z;
  }
  f32x4 lacc = {0.f, 0.f, 0.f, 0.f};  // denominator (all rows equal)
  float negms = 0.f;                  // = -max_tile0 * SCALE, set at it==0
  bf16x8 pbp[2];                      // P frags of previous tile
  bf16x8 vfp[4][2];                   // V frags of previous tile

  // 8 waves cover 64 rows: wave w stages rows w*8..w*8+7 (1 K + 1 V load)
  auto stage = [&](int t0, int buf) {
    int rb = w * 8;
    int row = rb + lr;  // row & 7 == lr
    const u16* ksrc =
        qkv + ((size_t)(t0 + row) * BATCH + b) * 3072 + 1024 + h * DHEAD + (ch ^ lr) * 8;
    gload_lds16(ksrc, &ks[buf][rb * 64]);
    const u16* vsrc = vt + ((size_t)bh * DHEAD + row) * S_LEN + t0 + (ch ^ lr) * 8;
    gload_lds16(vsrc, &vs[buf][rb * 64]);
  };

  stage(0, 0);
  asm volatile("s_waitcnt vmcnt(0)" ::: "memory");
  __builtin_amdgcn_s_barrier();

  for (int it = 0; it < S_LEN / 64; ++it) {
    int cur = it & 1;
    if (it + 1 < S_LEN / 64) {
      stage((it + 1) * 64, cur ^ 1);
      asm volatile("s_waitcnt vmcnt(2)" ::: "memory");  // prev iter's 2 loads landed
    } else {
      asm volatile("s_waitcnt vmcnt(0)" ::: "memory");
    }
    __builtin_amdgcn_s_barrier();

    // ---- QK^T(t) (swapped): scT[tt][r] = S_raw^T[16tt+4g+r][q0+l15] ----
    f32x4 scT[4];
#pragma unroll
    for (int tt = 0; tt < 4; tt++) {
      int row = tt * 16 + l15;
      bf16x8 kf0 = *(const bf16x8*)&ks[cur][row * 64 + ((g ^ (row & 7)) * 8)];
      bf16x8 kf1 = *(const bf16x8*)&ks[cur][row * 64 + (((4 + g) ^ (row & 7)) * 8)];
      f32x4 z = {0.f, 0.f, 0.f, 0.f};
      __builtin_amdgcn_s_setprio(1);
      z = mfma16(kf0, qf0, z);
      z = mfma16(kf1, qf1, z);
      __builtin_amdgcn_s_setprio(0);
      scT[tt] = z;
    }

    // ---- PV(t-1) + denominator: pure-register MFMA, independent of softmax(t) ----
    if (it > 0) {
      __builtin_amdgcn_s_setprio(1);
      lacc = mfma16(onef, pbp[0], lacc);
      lacc = mfma16(onef, pbp[1], lacc);
#pragma unroll
      for (int n = 0; n < 4; n++) {
        accT[n] = mfma16(vfp[n][0], pbp[0], accT[n]);
        accT[n] = mfma16(vfp[n][1], pbp[1], accT[n]);
      }
      __builtin_amdgcn_s_setprio(0);
    }

    // ---- load V(t) frags (consumed next iter); overlaps softmax VALU below ----
#pragma unroll
    for (int n = 0; n < 4; n++) {
      int vrow = n * 16 + l15;
      vfp[n][0] = *(const bf16x8*)&vs[cur][vrow * 64 + ((g ^ (vrow & 7)) * 8)];
      vfp[n][1] = *(const bf16x8*)&vs[cur][vrow * 64 + (((4 + g) ^ (vrow & 7)) * 8)];
    }

    // ---- softmax(t): frozen max, exp2, repack -> pbp (for next iter) ----
    if (it == 0) {
      float pm = fmaxf(fmaxf(scT[0][0], scT[0][1]), fmaxf(scT[0][2], scT[0][3]));
#pragma unroll
      for (int tt = 1; tt < 4; tt++)
        pm = fmaxf(pm, fmaxf(fmaxf(scT[tt][0], scT[tt][1]), fmaxf(scT[tt][2], scT[tt][3])));
      pm = fmaxf(pm, __shfl_xor(pm, 16));
      pm = fmaxf(pm, __shfl_xor(pm, 32));
      negms = -pm * SCALE;
    }
    float p[4][4];
#pragma unroll
    for (int tt = 0; tt < 4; tt++)
#pragma unroll
      for (int r = 0; r < 4; r++) p[tt][r] = __builtin_amdgcn_exp2f(fmaf(scT[tt][r], SCALE, negms));
    uint32_t P32[4][2];
#pragma unroll
    for (int tt = 0; tt < 4; tt++)
#pragma unroll
      for (int m = 0; m < 2; m++) P32[tt][m] = cvt_pk_bf16(p[tt][2 * m], p[tt][2 * m + 1]);
#pragma unroll
    for (int t5 = 0; t5 < 2; t5++)
#pragma unroll
      for (int m = 0; m < 2; m++) {
        asm("v_permlane32_swap_b32 %0, %1" : "+v"(P32[2 * t5][m]), "+v"(P32[2 * t5 + 1][m]));
        asm("v_permlane16_swap_b32 %0, %1" : "+v"(P32[2 * t5][m]), "+v"(P32[2 * t5 + 1][m]));
      }
#pragma unroll
    for (int s2 = 0; s2 < 2; s2++) {
      union { uint32_t u[4]; bf16x8 v; } uu;
      uu.u[0] = P32[2 * s2][0];
      uu.u[1] = P32[2 * s2][1];
      uu.u[2] = P32[2 * s2 + 1][0];
      uu.u[3] = P32[2 * s2 + 1][1];
      pbp[s2] = uu.v;
    }

    // deferred V reads must land before next iter's stage overwrites vs[cur]
    asm volatile("s_waitcnt lgkmcnt(0)" ::: "memory");
    __builtin_amdgcn_s_barrier();
  }

  // ---- epilogue: PV(last) ----
  lacc = mfma16(onef, pbp[0], lacc);
  lacc = mfma16(onef, pbp[1], lacc);
#pragma unroll
  for (int n = 0; n < 4; n++) {
    accT[n] = mfma16(vfp[n][0], pbp[0], accT[n]);
    accT[n] = mfma16(vfp[n][1], pbp[1], accT[n]);
  }

  float inv = 1.f / lacc[0];
  int srow = q0 + l15;
#pragma unroll
  for (int n = 0; n < 4; n++) {
    u16x4 o;
    o.x = f2bf(accT[n][0] * inv);
    o.y = f2bf(accT[n][1] * inv);
    o.z = f2bf(accT[n][2] * inv);
    o.w = f2bf(accT[n][3] * inv);
    *(u16x4*)(ctx + ((size_t)srow * BATCH + b) * DMODEL + h * DHEAD + n * 16 + 4 * g) = o;
  }
}

extern "C" void kernel_launch(void* const* d_in, const int* in_sizes, int n_in, void* d_out,
                              int out_size, void* d_ws, size_t ws_size, hipStream_t stream) {
  (void)in_sizes; (void)n_in; (void)out_size; (void)ws_size;
  const float* x    = (const float*)d_in[0];
  const float* wq   = (const float*)d_in[1];
  const float* wk   = (const float*)d_in[2];
  const float* wv   = (const float*)d_in[3];
  const float* wo   = (const float*)d_in[4];
  const float* ln1g = (const float*)d_in[5];
  const float* ln1b = (const float*)d_in[6];
  const float* ln2g = (const float*)d_in[7];
  const float* ln2b = (const float*)d_in[8];
  const float* w1   = (const float*)d_in[9];
  const float* b1   = (const float*)d_in[10];
  const float* w2   = (const float*)d_in[11];
  const float* b2   = (const float*)d_in[12];

  char* ws = (char*)d_ws;
  size_t off = 0;
  auto alloc = [&](size_t bytes) {
    void* p = ws + off;
    off += (bytes + 255) & ~(size_t)255;
    return p;
  };
  u16* yb    = (u16*)alloc((size_t)MROWS * DMODEL * 2);
  u16* wqkvt = (u16*)alloc((size_t)3072 * 1024 * 2);
  u16* wot   = (u16*)alloc((size_t)1024 * 1024 * 2);
  u16* w1t   = (u16*)alloc((size_t)4096 * 1024 * 2);
  u16* w2t   = (u16*)alloc((size_t)1024 * 4096 * 2);
  u16* qkvb  = (u16*)alloc((size_t)MROWS * 3072 * 2);
  u16* vtb   = (u16*)alloc((size_t)BATCH * NHEAD * DHEAD * S_LEN * 2);
  u16* ctxb  = (u16*)alloc((size_t)MROWS * DMODEL * 2);
  u16* x1b   = (u16*)alloc((size_t)MROWS * DMODEL * 2);  // bf16 residual x1
  u16* zb    = (u16*)alloc((size_t)MROWS * DMODEL * 2);
  u16* hb    = (u16*)alloc((size_t)MROWS * FFDIM * 2);

  // sublayer 0
  ln_kernel<<<MROWS, 256, 0, stream>>>(x, ln1g, ln1b, yb);
  transpose_all<<<12288, 256, 0, stream>>>(wq, wk, wv, wo, w1, w2, wqkvt, wot, w1t, w2t);

  gemm_bt<0, 128><<<dim3(3072 / 128, 4096 / 128), 256, 0, stream>>>(yb, wqkvt, qkvb, nullptr,
                                                                    nullptr, 4096, 3072, 1024);
  transpose_v<<<dim3(64, 2, 32), 256, 0, stream>>>(qkvb, vtb);
  attn_kernel<<<dim3(16, 32), 512, 0, stream>>>(qkvb, vtb, ctxb);
  // Wo: x1 = ctx@wo + x, stored bf16
  gemm_bt<5, 64><<<dim3(16, 32), 256, 0, stream>>>(ctxb, wot, x1b, nullptr, x, 4096, 1024, 1024);

  // sublayer 1
  ln_kernel_b<<<MROWS, 256, 0, stream>>>(x1b, ln2g, ln2b, zb);
  gemm_bt<2, 128><<<dim3(32, 32), 256, 0, stream>>>(zb, w1t, hb, b1, nullptr, 4096, 4096, 1024);
  // FFN2: out = h@w2 + b2 + x1 (bf16 res), fp32 out
  gemm_bt<6, 64><<<dim3(16, 32), 256, 0, stream>>>(hb, w2t, d_out, b2, x1b, 4096, 1024, 4096);
}

// Round 14
// 224.076 us; speedup vs baseline: 1.1369x; 1.0365x over previous
//
#include <hip/hip_runtime.h>
#include <hip/hip_bf16.h>
#include <stdint.h>

// Transformer layer: S=2048, B=2, D=1024, H=16, DH=64, FF=4096. fp32 in/out.
// Strategy: fp32 LN/softmax/accum, bf16 MFMA (16x16x32) for all GEMMs.
// R14: Wo/FFN2 at BM=64xBN=64 (1024 blocks = 4/CU, 16 waves/CU) for TLP.

#define S_LEN 2048
#define BATCH 2
#define DMODEL 1024
#define NHEAD 16
#define DHEAD 64
#define FFDIM 4096
#define MROWS (S_LEN * BATCH)  // 4096 rows, row index = s*B + b

typedef unsigned short u16;
typedef __attribute__((ext_vector_type(8))) __bf16 bf16x8;
typedef __attribute__((ext_vector_type(4))) float f32x4;
typedef __attribute__((ext_vector_type(4))) u16 u16x4;

__device__ inline u16 f2bf(float f) {
  union { float f; unsigned u; } v; v.f = f;
  unsigned r = v.u + 0x7fffu + ((v.u >> 16) & 1u);  // round-to-nearest-even
  return (u16)(r >> 16);
}

__device__ inline float bf2f(u16 u) {
  union { unsigned u; float f; } v;
  v.u = ((unsigned)u) << 16;
  return v.f;
}

__device__ inline f32x4 mfma16(bf16x8 a, bf16x8 b, f32x4 c) {
  return __builtin_amdgcn_mfma_f32_16x16x32_bf16(a, b, c, 0, 0, 0);
}

// async global->LDS, 16B per lane. LDS dest must be wave-uniform base; HW adds lane*16.
__device__ inline void gload_lds16(const u16* g, u16* l) {
  __builtin_amdgcn_global_load_lds(
      (const __attribute__((address_space(1))) unsigned int*)g,
      (__attribute__((address_space(3))) unsigned int*)l, 16, 0, 0);
}

__device__ inline uint32_t cvt_pk_bf16(float lo, float hi) {
  uint32_t r;
  asm("v_cvt_pk_bf16_f32 %0, %1, %2" : "=v"(r) : "v"(lo), "v"(hi));
  return r;
}

// ---------------- LayerNorm: fp32 in -> bf16 out ----------------
__global__ __launch_bounds__(256) void ln_kernel(const float* __restrict__ x,
                                                 const float* __restrict__ gam,
                                                 const float* __restrict__ bet,
                                                 u16* __restrict__ out) {
  int row = blockIdx.x;
  int tid = threadIdx.x;
  const float4* xr = (const float4*)(x + (size_t)row * DMODEL);
  float4 v = xr[tid];
  float s = v.x + v.y + v.z + v.w;
  float ss = v.x * v.x + v.y * v.y + v.z * v.z + v.w * v.w;
#pragma unroll
  for (int m = 1; m < 64; m <<= 1) {
    s += __shfl_xor(s, m);
    ss += __shfl_xor(ss, m);
  }
  __shared__ float red[8];
  int w = tid >> 6, lane = tid & 63;
  if (lane == 0) { red[w] = s; red[4 + w] = ss; }
  __syncthreads();
  s = red[0] + red[1] + red[2] + red[3];
  ss = red[4] + red[5] + red[6] + red[7];
  float mu = s * (1.f / DMODEL);
  float var = ss * (1.f / DMODEL) - mu * mu;
  float rstd = rsqrtf(var + 1e-5f);
  float4 gv = ((const float4*)gam)[tid];
  float4 bv = ((const float4*)bet)[tid];
  u16x4 o;
  o.x = f2bf((v.x - mu) * rstd * gv.x + bv.x);
  o.y = f2bf((v.y - mu) * rstd * gv.y + bv.y);
  o.z = f2bf((v.z - mu) * rstd * gv.z + bv.z);
  o.w = f2bf((v.w - mu) * rstd * gv.w + bv.w);
  *(u16x4*)(out + (size_t)row * DMODEL + tid * 4) = o;
}

// ---------------- LayerNorm: bf16 in -> bf16 out (for LN2 on bf16 x1) ----------------
__global__ __launch_bounds__(256) void ln_kernel_b(const u16* __restrict__ x,
                                                   const float* __restrict__ gam,
                                                   const float* __restrict__ bet,
                                                   u16* __restrict__ out) {
  int row = blockIdx.x;
  int tid = threadIdx.x;
  u16x4 uv = *(const u16x4*)(x + (size_t)row * DMODEL + tid * 4);
  float4 v;
  v.x = bf2f(uv.x); v.y = bf2f(uv.y); v.z = bf2f(uv.z); v.w = bf2f(uv.w);
  float s = v.x + v.y + v.z + v.w;
  float ss = v.x * v.x + v.y * v.y + v.z * v.z + v.w * v.w;
#pragma unroll
  for (int m = 1; m < 64; m <<= 1) {
    s += __shfl_xor(s, m);
    ss += __shfl_xor(ss, m);
  }
  __shared__ float red[8];
  int w = tid >> 6, lane = tid & 63;
  if (lane == 0) { red[w] = s; red[4 + w] = ss; }
  __syncthreads();
  s = red[0] + red[1] + red[2] + red[3];
  ss = red[4] + red[5] + red[6] + red[7];
  float mu = s * (1.f / DMODEL);
  float var = ss * (1.f / DMODEL) - mu * mu;
  float rstd = rsqrtf(var + 1e-5f);
  float4 gv = ((const float4*)gam)[tid];
  float4 bv = ((const float4*)bet)[tid];
  u16x4 o;
  o.x = f2bf((v.x - mu) * rstd * gv.x + bv.x);
  o.y = f2bf((v.y - mu) * rstd * gv.y + bv.y);
  o.z = f2bf((v.z - mu) * rstd * gv.z + bv.z);
  o.w = f2bf((v.w - mu) * rstd * gv.w + bv.w);
  *(u16x4*)(out + (size_t)row * DMODEL + tid * 4) = o;
}

// ---------------- fused weight transpose-cast: all 6 weights in ONE launch ----------------
__global__ __launch_bounds__(256) void transpose_all(const float* __restrict__ wq,
                                                     const float* __restrict__ wk,
                                                     const float* __restrict__ wv,
                                                     const float* __restrict__ wo,
                                                     const float* __restrict__ w1,
                                                     const float* __restrict__ w2,
                                                     u16* __restrict__ wqkvt, u16* __restrict__ wot,
                                                     u16* __restrict__ w1t, u16* __restrict__ w2t) {
  int idx = blockIdx.x;
  const float* in;
  u16* out;
  int R, C;
  if (idx < 3072) {
    int which = idx >> 10;
    in = (which == 0) ? wq : (which == 1) ? wk : wv;
    out = wqkvt + (size_t)which * 1024 * 1024;
    R = 1024; C = 1024;
    idx &= 1023;
  } else if (idx < 4096) {
    in = wo; out = wot; R = 1024; C = 1024; idx -= 3072;
  } else if (idx < 8192) {
    in = w1; out = w1t; R = 1024; C = 4096; idx -= 4096;
  } else {
    in = w2; out = w2t; R = 4096; C = 1024; idx -= 8192;
  }
  int ntx = C >> 5;
  int tc = idx % ntx, tr = idx / ntx;
  int c0 = tc * 32, r0 = tr * 32;
  __shared__ u16 tile[32][33];
  int tx = threadIdx.x & 31, grp = threadIdx.x >> 5;
#pragma unroll
  for (int i = 0; i < 4; i++) {
    int r = grp * 4 + i;
    tile[r][tx] = f2bf(in[(size_t)(r0 + r) * C + c0 + tx]);
  }
  __syncthreads();
#pragma unroll
  for (int i = 0; i < 4; i++) {
    int rr = grp * 4 + i;
    out[(size_t)(c0 + rr) * R + r0 + tx] = tile[tx][rr];
  }
}

// ---------------- V slice of qkv -> Vt[bh][dh][s] ----------------
__global__ __launch_bounds__(256) void transpose_v(const u16* __restrict__ qkv,
                                                   u16* __restrict__ vt) {
  __shared__ u16 tile[32][33];
  int bh = blockIdx.z;
  int b = bh >> 4;
  int s0 = blockIdx.x * 32, d0 = blockIdx.y * 32;
  int h = bh & 15;
  int tx = threadIdx.x & 31, grp = threadIdx.x >> 5;
#pragma unroll
  for (int i = 0; i < 4; i++) {
    int sl = grp * 4 + i;
    tile[sl][tx] = qkv[(size_t)((s0 + sl) * BATCH + b) * 3072 + 2048 + h * DHEAD + d0 + tx];
  }
  __syncthreads();
#pragma unroll
  for (int i = 0; i < 4; i++) {
    int dl = grp * 4 + i;
    vt[((size_t)bh * DHEAD + d0 + dl) * S_LEN + s0 + tx] = tile[tx][dl];
  }
}

// ---------------- GEMM (proven 2-phase, FROZEN sync): BK=64, XOR-swizzled LDS, counted vmcnt ----
// C[M][N] = A[M][K](bf16) @ Bt[N][K](bf16)^T.  BM in {128,64}, BN in {128,64}, 4 waves.
// Wave grid 2Mx2N; wave tile (BM/2)x(BN/2).  Loads/wave/stage = BM/32 + BN/32.
// MODE 0: bf16 out.                MODE 2: bf16 out = relu(acc + bias).
// MODE 5: bf16 out = acc + fp32 res.   MODE 6: fp32 out = acc + bias + bf16 res.
template <int MODE, int BM, int BN>
__global__ __launch_bounds__(256) void gemm_bt(const u16* __restrict__ A,
                                               const u16* __restrict__ Bt, void* __restrict__ Cout,
                                               const float* __restrict__ bias,
                                               const void* __restrict__ res, int M, int N, int K) {
  __shared__ __align__(16) u16 As[2][BM * 64];
  __shared__ __align__(16) u16 Bs[2][BN * 64];
  constexpr int NLOADS = BM / 32 + BN / 32;
  constexpr int MI = BM / 32;  // m-frags per wave (wave m-tile = BM/2 = MI*16)
  constexpr int NJ = BN / 32;  // n-frags per wave

  int nwg = gridDim.x * gridDim.y;
  int f = blockIdx.y * gridDim.x + blockIdx.x;
  int nf = ((nwg & 7) == 0) ? ((f & 7) * (nwg >> 3) + (f >> 3)) : f;
  int bx = nf % gridDim.x, by = nf / gridDim.x;

  int bm0 = by * BM, bn0 = bx * BN;
  int tid = threadIdx.x, w = tid >> 6, lane = tid & 63;
  int g = lane >> 4, l15 = lane & 15;
  int lr = lane >> 3, ch = lane & 7;
  int srcch = (ch ^ lr) * 8;  // pre-swizzled 16B-chunk column offset (rule 21c)
  int wm = (w >> 1) * (BM / 2), wn = (w & 1) * (BN / 2);

  f32x4 acc[MI][NJ];
#pragma unroll
  for (int i = 0; i < MI; i++)
#pragma unroll
    for (int j = 0; j < NJ; j++) {
      f32x4 z = {0.f, 0.f, 0.f, 0.f};
      acc[i][j] = z;
    }

  auto stage = [&](int k0, int buf) {
#pragma unroll
    for (int rd = 0; rd < BM / 32; rd++) {
      int rb = (rd * 4 + w) * 8;  // lane's row = rb + lr; row&7 == lr
      gload_lds16(A + (size_t)(bm0 + rb + lr) * K + k0 + srcch, &As[buf][rb * 64]);
    }
#pragma unroll
    for (int rd = 0; rd < BN / 32; rd++) {
      int rb = (rd * 4 + w) * 8;
      gload_lds16(Bt + (size_t)(bn0 + rb + lr) * K + k0 + srcch, &Bs[buf][rb * 64]);
    }
  };

  int nkt = K >> 6;
  stage(0, 0);
  asm volatile("s_waitcnt vmcnt(0)" ::: "memory");
  __builtin_amdgcn_s_barrier();

  for (int kt = 0; kt < nkt; ++kt) {
    int cur = kt & 1;
    if (kt + 1 < nkt) {
      stage((kt + 1) << 6, cur ^ 1);
      asm volatile("s_waitcnt vmcnt(%0)" ::"n"(NLOADS) : "memory");
    } else {
      asm volatile("s_waitcnt vmcnt(0)" ::: "memory");
    }
    __builtin_amdgcn_s_barrier();
#pragma unroll
    for (int kk = 0; kk < 2; kk++) {
      bf16x8 af[MI], bfr[NJ];
#pragma unroll
      for (int i = 0; i < MI; i++) {
        int row = wm + i * 16 + l15;
        af[i] = *(const bf16x8*)&As[cur][row * 64 + (((kk * 4 + g) ^ (row & 7)) * 8)];
      }
#pragma unroll
      for (int j = 0; j < NJ; j++) {
        int row = wn + j * 16 + l15;
        bfr[j] = *(const bf16x8*)&Bs[cur][row * 64 + (((kk * 4 + g) ^ (row & 7)) * 8)];
      }
#pragma unroll
      for (int i = 0; i < MI; i++)
#pragma unroll
        for (int j = 0; j < NJ; j++) acc[i][j] = mfma16(af[i], bfr[j], acc[i][j]);
    }
    __builtin_amdgcn_s_barrier();
  }

  // epilogue: D layout col = lane&15, row = 4*(lane>>4) + r
#pragma unroll
  for (int i = 0; i < MI; i++)
#pragma unroll
    for (int j = 0; j < NJ; j++) {
      int col = bn0 + wn + j * 16 + l15;
      float bval = (MODE == 2 || MODE == 6) ? bias[col] : 0.f;
#pragma unroll
      for (int r = 0; r < 4; r++) {
        int row = bm0 + wm + i * 16 + g * 4 + r;
        size_t idx = (size_t)row * N + col;
        float vacc = acc[i][j][r] + bval;
        if (MODE == 0)
          ((u16*)Cout)[idx] = f2bf(vacc);
        else if (MODE == 2)
          ((u16*)Cout)[idx] = f2bf(fmaxf(vacc, 0.f));
        else if (MODE == 5)
          ((u16*)Cout)[idx] = f2bf(vacc + ((const float*)res)[idx]);
        else if (MODE == 6)
          ((float*)Cout)[idx] = vacc + bf2f(((const u16*)res)[idx]);
      }
    }
}

// ---------------- flash attention v8 (FROZEN): deferred-PV + 8-wave blocks ----------------
// grid (S/128, B*H) XCD-chunked, 512 thr = 8 waves; wave owns 16 q rows (QBLK=128).
// Swapped QK, frozen max, ones-MFMA denominator, in-register P repack, deferred PV.
__global__ __launch_bounds__(512) void attn_kernel(const u16* __restrict__ qkv,
                                                   const u16* __restrict__ vt,
                                                   u16* __restrict__ ctx) {
  int nwg = gridDim.x * gridDim.y;  // 512
  int f = blockIdx.y * gridDim.x + blockIdx.x;
  int nf = (f & 7) * (nwg >> 3) + (f >> 3);
  int qblk = nf % gridDim.x, bh = nf / gridDim.x;
  int b = bh >> 4, h = bh & 15;
  int tid = threadIdx.x, w = tid >> 6, lane = tid & 63;
  int g = lane >> 4, l15 = lane & 15;
  int lr = lane >> 3, ch = lane & 7;
  int q0 = qblk * 128 + w * 16;
  const float SCALE = 0.125f * 1.44269504f;  // 1/sqrt(64) * log2(e)

  __shared__ __align__(16) u16 ks[2][64 * 64];
  __shared__ __align__(16) u16 vs[2][64 * 64];

  bf16x8 qf0, qf1;
  {
    const u16* qp = qkv + ((size_t)(q0 + l15) * BATCH + b) * 3072 + h * DHEAD;
    qf0 = *(const bf16x8*)(qp + g * 8);
    qf1 = *(const bf16x8*)(qp + 32 + g * 8);
  }
  bf16x8 onef;
  {
    union { u16 u[8]; bf16x8 v; } ou;
#pragma unroll
    for (int i = 0; i < 8; i++) ou.u[i] = 0x3F80;  // bf16 1.0
    onef = ou.v;
  }

  f32x4 accT[4];
#pragma unroll
  for (int n = 0; n < 4; n++) {
    f32x4 z = {0.f, 0.f, 0.f, 0.f};
    accT[n] = z;
  }
  f32x4 lacc = {0.f, 0.f, 0.f, 0.f};  // denominator (all rows equal)
  float negms = 0.f;                  // = -max_tile0 * SCALE, set at it==0
  bf16x8 pbp[2];                      // P frags of previous tile
  bf16x8 vfp[4][2];                   // V frags of previous tile

  // 8 waves cover 64 rows: wave w stages rows w*8..w*8+7 (1 K + 1 V load)
  auto stage = [&](int t0, int buf) {
    int rb = w * 8;
    int row = rb + lr;  // row & 7 == lr
    const u16* ksrc =
        qkv + ((size_t)(t0 + row) * BATCH + b) * 3072 + 1024 + h * DHEAD + (ch ^ lr) * 8;
    gload_lds16(ksrc, &ks[buf][rb * 64]);
    const u16* vsrc = vt + ((size_t)bh * DHEAD + row) * S_LEN + t0 + (ch ^ lr) * 8;
    gload_lds16(vsrc, &vs[buf][rb * 64]);
  };

  stage(0, 0);
  asm volatile("s_waitcnt vmcnt(0)" ::: "memory");
  __builtin_amdgcn_s_barrier();

  for (int it = 0; it < S_LEN / 64; ++it) {
    int cur = it & 1;
    if (it + 1 < S_LEN / 64) {
      stage((it + 1) * 64, cur ^ 1);
      asm volatile("s_waitcnt vmcnt(2)" ::: "memory");  // prev iter's 2 loads landed
    } else {
      asm volatile("s_waitcnt vmcnt(0)" ::: "memory");
    }
    __builtin_amdgcn_s_barrier();

    // ---- QK^T(t) (swapped): scT[tt][r] = S_raw^T[16tt+4g+r][q0+l15] ----
    f32x4 scT[4];
#pragma unroll
    for (int tt = 0; tt < 4; tt++) {
      int row = tt * 16 + l15;
      bf16x8 kf0 = *(const bf16x8*)&ks[cur][row * 64 + ((g ^ (row & 7)) * 8)];
      bf16x8 kf1 = *(const bf16x8*)&ks[cur][row * 64 + (((4 + g) ^ (row & 7)) * 8)];
      f32x4 z = {0.f, 0.f, 0.f, 0.f};
      __builtin_amdgcn_s_setprio(1);
      z = mfma16(kf0, qf0, z);
      z = mfma16(kf1, qf1, z);
      __builtin_amdgcn_s_setprio(0);
      scT[tt] = z;
    }

    // ---- PV(t-1) + denominator: pure-register MFMA, independent of softmax(t) ----
    if (it > 0) {
      __builtin_amdgcn_s_setprio(1);
      lacc = mfma16(onef, pbp[0], lacc);
      lacc = mfma16(onef, pbp[1], lacc);
#pragma unroll
      for (int n = 0; n < 4; n++) {
        accT[n] = mfma16(vfp[n][0], pbp[0], accT[n]);
        accT[n] = mfma16(vfp[n][1], pbp[1], accT[n]);
      }
      __builtin_amdgcn_s_setprio(0);
    }

    // ---- load V(t) frags (consumed next iter); overlaps softmax VALU below ----
#pragma unroll
    for (int n = 0; n < 4; n++) {
      int vrow = n * 16 + l15;
      vfp[n][0] = *(const bf16x8*)&vs[cur][vrow * 64 + ((g ^ (vrow & 7)) * 8)];
      vfp[n][1] = *(const bf16x8*)&vs[cur][vrow * 64 + (((4 + g) ^ (vrow & 7)) * 8)];
    }

    // ---- softmax(t): frozen max, exp2, repack -> pbp (for next iter) ----
    if (it == 0) {
      float pm = fmaxf(fmaxf(scT[0][0], scT[0][1]), fmaxf(scT[0][2], scT[0][3]));
#pragma unroll
      for (int tt = 1; tt < 4; tt++)
        pm = fmaxf(pm, fmaxf(fmaxf(scT[tt][0], scT[tt][1]), fmaxf(scT[tt][2], scT[tt][3])));
      pm = fmaxf(pm, __shfl_xor(pm, 16));
      pm = fmaxf(pm, __shfl_xor(pm, 32));
      negms = -pm * SCALE;
    }
    float p[4][4];
#pragma unroll
    for (int tt = 0; tt < 4; tt++)
#pragma unroll
      for (int r = 0; r < 4; r++) p[tt][r] = __builtin_amdgcn_exp2f(fmaf(scT[tt][r], SCALE, negms));
    uint32_t P32[4][2];
#pragma unroll
    for (int tt = 0; tt < 4; tt++)
#pragma unroll
      for (int m = 0; m < 2; m++) P32[tt][m] = cvt_pk_bf16(p[tt][2 * m], p[tt][2 * m + 1]);
#pragma unroll
    for (int t5 = 0; t5 < 2; t5++)
#pragma unroll
      for (int m = 0; m < 2; m++) {
        asm("v_permlane32_swap_b32 %0, %1" : "+v"(P32[2 * t5][m]), "+v"(P32[2 * t5 + 1][m]));
        asm("v_permlane16_swap_b32 %0, %1" : "+v"(P32[2 * t5][m]), "+v"(P32[2 * t5 + 1][m]));
      }
#pragma unroll
    for (int s2 = 0; s2 < 2; s2++) {
      union { uint32_t u[4]; bf16x8 v; } uu;
      uu.u[0] = P32[2 * s2][0];
      uu.u[1] = P32[2 * s2][1];
      uu.u[2] = P32[2 * s2 + 1][0];
      uu.u[3] = P32[2 * s2 + 1][1];
      pbp[s2] = uu.v;
    }

    // deferred V reads must land before next iter's stage overwrites vs[cur]
    asm volatile("s_waitcnt lgkmcnt(0)" ::: "memory");
    __builtin_amdgcn_s_barrier();
  }

  // ---- epilogue: PV(last) ----
  lacc = mfma16(onef, pbp[0], lacc);
  lacc = mfma16(onef, pbp[1], lacc);
#pragma unroll
  for (int n = 0; n < 4; n++) {
    accT[n] = mfma16(vfp[n][0], pbp[0], accT[n]);
    accT[n] = mfma16(vfp[n][1], pbp[1], accT[n]);
  }

  float inv = 1.f / lacc[0];
  int srow = q0 + l15;
#pragma unroll
  for (int n = 0; n < 4; n++) {
    u16x4 o;
    o.x = f2bf(accT[n][0] * inv);
    o.y = f2bf(accT[n][1] * inv);
    o.z = f2bf(accT[n][2] * inv);
    o.w = f2bf(accT[n][3] * inv);
    *(u16x4*)(ctx + ((size_t)srow * BATCH + b) * DMODEL + h * DHEAD + n * 16 + 4 * g) = o;
  }
}

extern "C" void kernel_launch(void* const* d_in, const int* in_sizes, int n_in, void* d_out,
                              int out_size, void* d_ws, size_t ws_size, hipStream_t stream) {
  (void)in_sizes; (void)n_in; (void)out_size; (void)ws_size;
  const float* x    = (const float*)d_in[0];
  const float* wq   = (const float*)d_in[1];
  const float* wk   = (const float*)d_in[2];
  const float* wv   = (const float*)d_in[3];
  const float* wo   = (const float*)d_in[4];
  const float* ln1g = (const float*)d_in[5];
  const float* ln1b = (const float*)d_in[6];
  const float* ln2g = (const float*)d_in[7];
  const float* ln2b = (const float*)d_in[8];
  const float* w1   = (const float*)d_in[9];
  const float* b1   = (const float*)d_in[10];
  const float* w2   = (const float*)d_in[11];
  const float* b2   = (const float*)d_in[12];

  char* ws = (char*)d_ws;
  size_t off = 0;
  auto alloc = [&](size_t bytes) {
    void* p = ws + off;
    off += (bytes + 255) & ~(size_t)255;
    return p;
  };
  u16* yb    = (u16*)alloc((size_t)MROWS * DMODEL * 2);
  u16* wqkvt = (u16*)alloc((size_t)3072 * 1024 * 2);
  u16* wot   = (u16*)alloc((size_t)1024 * 1024 * 2);
  u16* w1t   = (u16*)alloc((size_t)4096 * 1024 * 2);
  u16* w2t   = (u16*)alloc((size_t)1024 * 4096 * 2);
  u16* qkvb  = (u16*)alloc((size_t)MROWS * 3072 * 2);
  u16* vtb   = (u16*)alloc((size_t)BATCH * NHEAD * DHEAD * S_LEN * 2);
  u16* ctxb  = (u16*)alloc((size_t)MROWS * DMODEL * 2);
  u16* x1b   = (u16*)alloc((size_t)MROWS * DMODEL * 2);  // bf16 residual x1
  u16* zb    = (u16*)alloc((size_t)MROWS * DMODEL * 2);
  u16* hb    = (u16*)alloc((size_t)MROWS * FFDIM * 2);

  // sublayer 0
  ln_kernel<<<MROWS, 256, 0, stream>>>(x, ln1g, ln1b, yb);
  transpose_all<<<12288, 256, 0, stream>>>(wq, wk, wv, wo, w1, w2, wqkvt, wot, w1t, w2t);

  gemm_bt<0, 128, 128><<<dim3(3072 / 128, 4096 / 128), 256, 0, stream>>>(
      yb, wqkvt, qkvb, nullptr, nullptr, 4096, 3072, 1024);
  transpose_v<<<dim3(64, 2, 32), 256, 0, stream>>>(qkvb, vtb);
  attn_kernel<<<dim3(16, 32), 512, 0, stream>>>(qkvb, vtb, ctxb);
  // Wo: x1 = ctx@wo + x, stored bf16.  64x64 tiles -> 1024 blocks = 4/CU.
  gemm_bt<5, 64, 64><<<dim3(1024 / 64, 4096 / 64), 256, 0, stream>>>(ctxb, wot, x1b, nullptr, x,
                                                                     4096, 1024, 1024);

  // sublayer 1
  ln_kernel_b<<<MROWS, 256, 0, stream>>>(x1b, ln2g, ln2b, zb);
  gemm_bt<2, 128, 128><<<dim3(32, 32), 256, 0, stream>>>(zb, w1t, hb, b1, nullptr, 4096, 4096,
                                                         1024);
  // FFN2: out = h@w2 + b2 + x1 (bf16 res), fp32 out.  64x64 tiles -> 1024 blocks = 4/CU.
  gemm_bt<6, 64, 64><<<dim3(1024 / 64, 4096 / 64), 256, 0, stream>>>(hb, w2t, d_out, b2, x1b, 4096,
                                                                     1024, 4096);
}